// Round 13
// baseline (3548.690 us; speedup 1.0000x reference)
//
#include <hip/hip_runtime.h>
#include <stdint.h>

#define BB 512
#define TT 64
#define OBSD 1024
#define ACTD 32
#define HD 1024
#define SD 64
#define BT (BB*TT)
#define G3 (3*HD)
#define STRD ((long)TT*HD)

typedef unsigned int uint32;
typedef unsigned long long ull;
typedef unsigned short u16;
typedef __attribute__((ext_vector_type(8))) short bf16x8;
typedef __attribute__((ext_vector_type(4))) float f32x4;

__device__ __forceinline__ float bf2f(u16 v){ uint32_t u = ((uint32_t)v)<<16; return __builtin_bit_cast(float,u); }
__device__ __forceinline__ u16 f2bf(float f){ uint32_t u = __builtin_bit_cast(uint32_t,f); uint32_t r = (u + 0x7FFFu + ((u>>16)&1u))>>16; return (u16)r; }
__device__ __forceinline__ float sigm(float x){ return 1.f/(1.f+expf(-x)); }
#define MFMA __builtin_amdgcn_mfma_f32_16x16x32_bf16

// width-16 async global->LDS
__device__ __forceinline__ void gload16(const u16* g, u16* l){
  __builtin_amdgcn_global_load_lds(
      (const __attribute__((address_space(1))) u16*)g,
      (__attribute__((address_space(3))) u16*)l, 16, 0, 0);
}

// ---------- f32 -> bf16 convert (RNE) ----------
__global__ void cvt_kernel(const float* __restrict__ in, u16* __restrict__ out, long n){
  long i = (long)blockIdx.x*blockDim.x + threadIdx.x;
  long st = (long)gridDim.x*blockDim.x;
  for (; i<n; i+=st) out[i] = f2bf(in[i]);
}

// ---------- generic bf16 MFMA GEMM (r11, gload_lds dbuf, tested) ----------
struct GemmP {
  const u16* a0; const u16* a1; const u16* a2;
  const u16* b0; const u16* b1; const u16* b2;
  long lda0, lda1, lda2, ldb0, ldb1, ldb2;
  int kc0, kc1, kc2, kcPerZ;
  float* cf; u16* cb;
  long ldc, ldcb, zstride;
  const float* bias0; const float* bias1;
  int relu;
};

template<int BM,int BN>
__global__ __launch_bounds__(256) void gemm_bf16(GemmP p){
  __shared__ __align__(16) u16 sAB[2][(BM+BN)*32];
  const int m0 = blockIdx.y*BM, n0 = blockIdx.x*BN;
  const int tid = threadIdx.x, lane = tid&63, wave = tid>>6;
  const int wm = (wave>>1)*(BM/2), wn = (wave&1)*(BN/2);
  constexpr int FM = BM/32, FN = BN/32;
  f32x4 acc[FM][FN] = {};
  const int cbeg = blockIdx.z*p.kcPerZ;
  int cend = cbeg + p.kcPerZ; if (cend > p.kc2) cend = p.kc2;
  const int kg = lane>>4, lr = lane&15;
  const int srow = lane>>2, scol = (lane&3)*8;

  auto STAGE = [&](int buf, int c){
    const u16* ap; const u16* bp; long lda, ldb; int kofs;
    if (c < p.kc0){ ap=p.a0; bp=p.b0; lda=p.lda0; ldb=p.ldb0; kofs=c*32; }
    else if (c < p.kc1){ ap=p.a1; bp=p.b1; lda=p.lda1; ldb=p.ldb1; kofs=(c-p.kc0)*32; }
    else { ap=p.a2; bp=p.b2; lda=p.lda2; ldb=p.ldb2; kofs=(c-p.kc1)*32; }
    u16* base = sAB[buf];
    #pragma unroll
    for (int it=0; it<BM/64; ++it){
      int row = it*64 + wave*16 + srow;
      gload16(ap + (long)(m0+row)*lda + kofs + scol,
              base + (it*64 + wave*16)*32);
    }
    #pragma unroll
    for (int it=0; it<BN/64; ++it){
      int row = it*64 + wave*16 + srow;
      gload16(bp + (long)(n0+row)*ldb + kofs + scol,
              base + BM*32 + (it*64 + wave*16)*32);
    }
  };

  STAGE(0, cbeg);
  for (int c=cbeg;c<cend;++c){
    const int cur = (c-cbeg)&1;
    asm volatile("s_waitcnt vmcnt(0)" ::: "memory");
    __syncthreads();
    if (c+1 < cend) STAGE(cur^1, c+1);
    const u16* sA = sAB[cur];
    const u16* sB = sAB[cur] + BM*32;
    bf16x8 af[FM], bfv[FN];
    #pragma unroll
    for (int i=0;i<FM;++i) af[i] = *(const bf16x8*)&sA[(wm+i*16+lr)*32 + kg*8];
    #pragma unroll
    for (int j=0;j<FN;++j) bfv[j] = *(const bf16x8*)&sB[(wn+j*16+lr)*32 + kg*8];
    #pragma unroll
    for (int i=0;i<FM;++i)
      #pragma unroll
      for (int j=0;j<FN;++j)
        acc[i][j] = MFMA(af[i], bfv[j], acc[i][j], 0,0,0);
    __syncthreads();
  }
  const bool partial = (gridDim.z > 1);
  float* cf = p.cf ? (p.cf + (partial ? (long)blockIdx.z*p.zstride : 0)) : nullptr;
  #pragma unroll
  for (int i=0;i<FM;++i){
    #pragma unroll
    for (int j=0;j<FN;++j){
      const int gr0 = m0 + wm + i*16 + kg*4;
      const int gc = n0 + wn + j*16 + lr;
      float bias = 0.f;
      if (!partial){
        if (p.bias0) bias += p.bias0[gc];
        if (p.bias1) bias += p.bias1[gc];
      }
      #pragma unroll
      for (int r=0;r<4;++r){
        float v = acc[i][j][r] + bias;
        if (p.relu) v = fmaxf(v, 0.f);
        const long row = gr0 + r;
        if (cf) cf[row*p.ldc + gc] = v;
        if (p.cb) p.cb[row*p.ldcb + gc] = f2bf(v);
      }
    }
  }
}

// ================= persistent cooperative scans =================
struct ScanArgs {
  const u16* act; const u16* Wih; const u16* Whh;
  const float* b_ih; const float* b_hh;
  const u16* Wpos; const float* qemb; const float* eps;
  u16* det; u16* sto; float* qm; float* qs;
  uint32* slots; const u16* zeroB;
};

// Group-local (32-block) arrive-by-store barrier (r9-proven primitive).
__device__ __forceinline__ void gsync_g(uint32* slots, int m, int n, uint32 val){
  asm volatile("s_waitcnt vmcnt(0)" ::: "memory");
  __syncthreads();
  if (threadIdx.x == 0)
    __hip_atomic_store(&slots[m*64 + n], val, __ATOMIC_RELAXED, __HIP_MEMORY_SCOPE_AGENT);
  if (threadIdx.x < 32){
    while (__hip_atomic_load(&slots[m*64 + threadIdx.x], __ATOMIC_RELAXED,
                             __HIP_MEMORY_SCOPE_AGENT) < val)
      __builtin_amdgcn_s_sleep(2);
  }
  __syncthreads();
}

// ---------------- scan32: 512 blocks (2/CU), BM=32 rows, BK=64 ----------------
#define SA3 76   // 152B row stride

__global__ __launch_bounds__(256, 2) void scan_kernel32(ScanArgs A){
  __shared__ __align__(16) u16 lds[(32+96)*SA3];
  u16* sA = lds; u16* sB = lds + 32*SA3;
  float* pf = (float*)lds;    // posterior reduce aliases gates tile (dead then)
  const int bid = blockIdx.x;
  const int tid = threadIdx.x, lane = tid&63, wave = tid>>6;
  const int lr = lane&15, kg = lane>>4;
  const int n = bid&31, m = bid>>5;       // 16 m-groups x 32 n-blocks
  const int m0 = m*32, h0 = n*32;
  const int wrow = (wave&1)*16, wcol = (wave>>1)*16;

  const int srow8 = tid>>3;          // 0..31
  const int scu8  = (tid&7)*8;       // 0..56

  // swapped-operand C layout: lane owns batch row (lr) x 4 consecutive h (kg*4+reg)
  const int h4 = h0 + wcol + kg*4;
  float bir[4], bhr[4], biz[4], bhz[4], bin[4], bhn[4];
  #pragma unroll
  for (int r=0;r<4;++r){
    bir[r]=A.b_ih[h4+r];      bhr[r]=A.b_hh[h4+r];
    biz[r]=A.b_ih[HD+h4+r];   bhz[r]=A.b_hh[HD+h4+r];
    bin[r]=A.b_ih[2*HD+h4+r]; bhn[r]=A.b_hh[2*HD+h4+r];
  }

  // distributed posterior tile: s-tile pj (16 s), row-tile prt (4 rows)
  const int pj = n & 3, prt = n >> 2;

  float dreg[4] = {0.f,0.f,0.f,0.f};
  const bf16x8 zerov = {};

  bf16x8 pa, pb[3];
  auto loadgt = [&](int tt, int g){
    if (g < 16){
      if (tt > 0)
        pa = *(const bf16x8*)(A.det + (long)(m0+srow8)*STRD + (long)(tt-1)*HD + g*64 + scu8);
      else pa = zerov;
      #pragma unroll
      for (int i=0;i<3;++i)
        pb[i] = *(const bf16x8*)(A.Whh + (long)(i*HD + h0 + srow8)*HD + g*64 + scu8);
    } else if (g == 16){
      if (tt > 0)
        pa = *(const bf16x8*)(A.sto + (long)(m0+srow8)*((long)TT*SD) + (long)(tt-1)*SD + scu8);
      else pa = zerov;
      #pragma unroll
      for (int i=0;i<3;++i)
        pb[i] = *(const bf16x8*)(A.Wih + (long)(i*HD + h0 + srow8)*96 + scu8);
    } else {
      if (scu8 < 32){
        pa = *(const bf16x8*)(A.act + (long)(m0+srow8)*((long)TT*ACTD) + (long)tt*ACTD + scu8);
        #pragma unroll
        for (int i=0;i<3;++i)
          pb[i] = *(const bf16x8*)(A.Wih + (long)(i*HD + h0 + srow8)*96 + 64 + scu8);
      } else {
        pa = zerov;
        pb[0]=zerov; pb[1]=zerov; pb[2]=zerov;
      }
    }
  };

  loadgt(0, 0);
  for (int t=0; t<TT; ++t){
    // ---------------- gates GEMM: 18 K-groups of 64 ----------------
    f32x4 aR={}, aZ={}, aNd={}, aNx={};
    for (int g=0; g<18; ++g){
      __syncthreads();
      *(bf16x8*)&sA[srow8*SA3 + scu8] = pa;
      #pragma unroll
      for (int i=0;i<3;++i) *(bf16x8*)&sB[(srow8 + i*32)*SA3 + scu8] = pb[i];
      if (g < 17) loadgt(t, g+1);
      __syncthreads();
      #pragma unroll
      for (int k=0;k<2;++k){
        bf16x8 av = *(const bf16x8*)&sA[(wrow+lr)*SA3 + k*32 + kg*8];
        bf16x8 b0 = *(const bf16x8*)&sB[(wcol+lr)*SA3 + k*32 + kg*8];
        bf16x8 b1 = *(const bf16x8*)&sB[(32+wcol+lr)*SA3 + k*32 + kg*8];
        bf16x8 b2 = *(const bf16x8*)&sB[(64+wcol+lr)*SA3 + k*32 + kg*8];
        aR = MFMA(b0,av,aR,0,0,0);
        aZ = MFMA(b1,av,aZ,0,0,0);
        if (g<16) aNd = MFMA(b2,av,aNd,0,0,0);
        else      aNx = MFMA(b2,av,aNx,0,0,0);
      }
    }
    // GRU epilogue; det written write-through (8B granules)
    {
      const long brow = m0 + wrow + lr;
      u16 pk[4];
      #pragma unroll
      for (int r=0;r<4;++r){
        float rr = sigm(aR[r]+bir[r]+bhr[r]);
        float z  = sigm(aZ[r]+biz[r]+bhz[r]);
        float nn = tanhf(aNx[r]+bin[r] + rr*(aNd[r]+bhn[r]));
        float d = (1.f - z)*nn + z*dreg[r];
        dreg[r] = d;
        pk[r] = f2bf(d);
      }
      ull pv; __builtin_memcpy(&pv, pk, 8);
      __hip_atomic_store((ull*)(A.det + brow*STRD + (long)t*HD + h4), pv,
                         __ATOMIC_RELAXED, __HIP_MEMORY_SCOPE_AGENT);
    }
    gsync_g(A.slots, m, n, (uint32)(2*t+1));

    // ---------------- distributed posterior: 4 rows x (16 mean + 16 std) ----------------
    {
      f32x4 accM = {}, accS = {};
      const int k0 = wave*256;
      const u16* arow = A.det + (long)(m0 + prt*4 + (lr&3))*STRD + (long)t*HD + k0 + kg*8;
      const u16* bm = A.Wpos + (long)(pj*16 + lr)*(2*HD) + k0 + kg*8;
      const u16* bs = A.Wpos + (long)(64 + pj*16 + lr)*(2*HD) + k0 + kg*8;
      #pragma unroll
      for (int kk=0; kk<8; ++kk){
        bf16x8 af = *(const bf16x8*)(arow + kk*32);
        accM = MFMA(af, *(const bf16x8*)(bm + kk*32), accM, 0,0,0);
        accS = MFMA(af, *(const bf16x8*)(bs + kk*32), accS, 0,0,0);
      }
      #pragma unroll
      for (int r=0;r<4;++r){
        int rowt = kg*4 + r;
        pf[wave*512 + rowt*16 + lr]       = accM[r];
        pf[wave*512 + 256 + rowt*16 + lr] = accS[r];
      }
      __syncthreads();
      if (tid < 32){
        const int row = tid>>3;        // 0..3 (C rows 4..15 are duplicates)
        const int s2 = (tid&7)*2;
        const long grow = m0 + prt*4 + row;
        const float* qe = A.qemb + grow*((long)TT*128) + (long)t*128;
        const float* ep = A.eps  + grow*((long)TT*SD) + (long)t*SD;
        u16 spk[2];
        #pragma unroll
        for (int i=0;i<2;++i){
          int sl = s2 + i, sg = pj*16 + sl;
          float mean = pf[row*16+sl] + pf[512+row*16+sl] + pf[1024+row*16+sl] + pf[1536+row*16+sl];
          float rsv  = pf[256+row*16+sl] + pf[768+row*16+sl] + pf[1280+row*16+sl] + pf[1792+row*16+sl];
          mean += qe[sg];
          rsv  += qe[64+sg];
          float sp = fmaxf(rsv,0.f) + log1pf(expf(-fabsf(rsv)));
          float qs_ = sp + 1e-4f;
          float st = mean + ep[sg]*qs_;
          A.qm[grow*((long)TT*SD) + (long)t*SD + sg] = mean;
          A.qs[grow*((long)TT*SD) + (long)t*SD + sg] = qs_;
          spk[i] = f2bf(st);
        }
        uint32 pv; __builtin_memcpy(&pv, spk, 4);
        __hip_atomic_store((uint32*)(A.sto + grow*((long)TT*SD) + (long)t*SD + pj*16 + s2), pv,
                           __ATOMIC_RELAXED, __HIP_MEMORY_SCOPE_AGENT);
      }
      __syncthreads();
    }
    // prefetch next step's gates group 0 (det(t) ready); overlaps barrier-2 wait
    if (t+1 < TT) loadgt(t+1, 0);
    gsync_g(A.slots, m, n, (uint32)(2*t+2));
  }
}

// ---------------- scan64: r11 verbatim (256 blocks, 1/CU) — fallback tier 2 ----------------
#define SA2 152

__global__ __launch_bounds__(256, 1) void scan_kernel64(ScanArgs A){
  __shared__ __align__(16) u16 lds[(64+96)*SA2];
  u16* sA = lds; u16* sB = lds + 64*SA2;
  float* pf = (float*)lds;
  const int bid = blockIdx.x;
  const int tid = threadIdx.x, lane = tid&63, wave = tid>>6;
  const int lr = lane&15, kg = lane>>4;
  const int n = bid&31, m = bid>>5;
  const int m0 = m*64, h0 = n*32;
  const int wrow = (wave&1)*32, wcol = (wave>>1)*16;

  const int srow = tid>>4;
  const int scu  = (tid&15)*8;

  long whhb[6], wihb[6];
  #pragma unroll
  for (int i=0;i<6;++i){
    int br = srow + i*16;
    int gate = br>>5, hr = br&31;
    whhb[i] = (long)(gate*HD + h0 + hr)*HD + scu;
    wihb[i] = (long)(gate*HD + h0 + hr)*96 + scu;
  }

  const int h4 = h0 + wcol + kg*4;
  float bir[4], bhr[4], biz[4], bhz[4], bin[4], bhn[4];
  #pragma unroll
  for (int r=0;r<4;++r){
    bir[r]=A.b_ih[h4+r];      bhr[r]=A.b_hh[h4+r];
    biz[r]=A.b_ih[HD+h4+r];   bhz[r]=A.b_hh[HD+h4+r];
    bin[r]=A.b_ih[2*HD+h4+r]; bhn[r]=A.b_hh[2*HD+h4+r];
  }

  const int pj = n & 3, prt = n >> 2;

  float dreg[2][4] = {{0.f,0.f,0.f,0.f},{0.f,0.f,0.f,0.f}};
  const bf16x8 zerov = {};

  bf16x8 pa[4], pb[6];
  auto loadgt = [&](int tt, int g){
    if (g < 8){
      if (tt > 0){
        const u16* s = A.det + (long)(tt-1)*HD + g*128 + scu;
        #pragma unroll
        for (int j=0;j<4;++j) pa[j] = *(const bf16x8*)(s + (long)(m0+srow+16*j)*STRD);
      } else { pa[0]=zerov; pa[1]=zerov; pa[2]=zerov; pa[3]=zerov; }
      #pragma unroll
      for (int i=0;i<6;++i) pb[i] = *(const bf16x8*)(A.Whh + whhb[i] + g*128);
    } else {
      if (scu < 64){
        if (tt > 0){
          #pragma unroll
          for (int j=0;j<4;++j)
            pa[j] = *(const bf16x8*)(A.sto + (long)(m0+srow+16*j)*((long)TT*SD) + (long)(tt-1)*SD + scu);
        } else { pa[0]=zerov; pa[1]=zerov; pa[2]=zerov; pa[3]=zerov; }
      } else if (scu < 96){
        #pragma unroll
        for (int j=0;j<4;++j)
          pa[j] = *(const bf16x8*)(A.act + (long)(m0+srow+16*j)*((long)TT*ACTD) + (long)tt*ACTD + (scu-64));
      } else { pa[0]=zerov; pa[1]=zerov; pa[2]=zerov; pa[3]=zerov; }
      #pragma unroll
      for (int i=0;i<6;++i) pb[i] = (scu < 96) ? *(const bf16x8*)(A.Wih + wihb[i]) : zerov;
    }
  };

  loadgt(0, 0);
  for (int t=0; t<TT; ++t){
    f32x4 aR[2]={}, aZ[2]={}, aNd[2]={}, aNx[2]={};
    for (int g=0; g<9; ++g){
      __syncthreads();
      #pragma unroll
      for (int j=0;j<4;++j) *(bf16x8*)&sA[(srow+16*j)*SA2 + scu] = pa[j];
      #pragma unroll
      for (int i=0;i<6;++i) *(bf16x8*)&sB[(srow+16*i)*SA2 + scu] = pb[i];
      if (g < 8) loadgt(t, g+1);
      __syncthreads();
      #pragma unroll
      for (int k=0;k<4;++k){
        bf16x8 a0v = *(const bf16x8*)&sA[(wrow+lr)*SA2 + k*32 + kg*8];
        bf16x8 a1v = *(const bf16x8*)&sA[(wrow+16+lr)*SA2 + k*32 + kg*8];
        bf16x8 b0 = *(const bf16x8*)&sB[(wcol+lr)*SA2 + k*32 + kg*8];
        bf16x8 b1 = *(const bf16x8*)&sB[(32+wcol+lr)*SA2 + k*32 + kg*8];
        bf16x8 b2 = *(const bf16x8*)&sB[(64+wcol+lr)*SA2 + k*32 + kg*8];
        aR[0] = MFMA(b0,a0v,aR[0],0,0,0); aR[1] = MFMA(b0,a1v,aR[1],0,0,0);
        aZ[0] = MFMA(b1,a0v,aZ[0],0,0,0); aZ[1] = MFMA(b1,a1v,aZ[1],0,0,0);
        if (g<8){ aNd[0] = MFMA(b2,a0v,aNd[0],0,0,0); aNd[1] = MFMA(b2,a1v,aNd[1],0,0,0); }
        else    { aNx[0] = MFMA(b2,a0v,aNx[0],0,0,0); aNx[1] = MFMA(b2,a1v,aNx[1],0,0,0); }
      }
    }
    #pragma unroll
    for (int rf=0;rf<2;++rf){
      const long brow = m0 + wrow + rf*16 + lr;
      u16 pk[4];
      #pragma unroll
      for (int r=0;r<4;++r){
        float rr = sigm(aR[rf][r]+bir[r]+bhr[r]);
        float z  = sigm(aZ[rf][r]+biz[r]+bhz[r]);
        float nn = tanhf(aNx[rf][r]+bin[r] + rr*(aNd[rf][r]+bhn[r]));
        float d = (1.f - z)*nn + z*dreg[rf][r];
        dreg[rf][r] = d;
        pk[r] = f2bf(d);
      }
      ull pv; __builtin_memcpy(&pv, pk, 8);
      __hip_atomic_store((ull*)(A.det + brow*STRD + (long)t*HD + h4), pv,
                         __ATOMIC_RELAXED, __HIP_MEMORY_SCOPE_AGENT);
    }
    gsync_g(A.slots, m, n, (uint32)(2*t+1));
    {
      f32x4 accM = {}, accS = {};
      const int k0 = wave*256;
      const u16* arow = A.det + (long)(m0 + prt*8 + (lr&7))*STRD + (long)t*HD + k0 + kg*8;
      const u16* bm = A.Wpos + (long)(pj*16 + lr)*(2*HD) + k0 + kg*8;
      const u16* bs = A.Wpos + (long)(64 + pj*16 + lr)*(2*HD) + k0 + kg*8;
      #pragma unroll
      for (int kk=0; kk<8; ++kk){
        bf16x8 af = *(const bf16x8*)(arow + kk*32);
        accM = MFMA(af, *(const bf16x8*)(bm + kk*32), accM, 0,0,0);
        accS = MFMA(af, *(const bf16x8*)(bs + kk*32), accS, 0,0,0);
      }
      #pragma unroll
      for (int r=0;r<4;++r){
        int rowt = kg*4 + r;
        pf[wave*512 + rowt*16 + lr]       = accM[r];
        pf[wave*512 + 256 + rowt*16 + lr] = accS[r];
      }
      __syncthreads();
      if (tid < 64){
        const int row = tid>>3;
        const int s2 = (tid&7)*2;
        const long grow = m0 + prt*8 + row;
        const float* qe = A.qemb + grow*((long)TT*128) + (long)t*128;
        const float* ep = A.eps  + grow*((long)TT*SD) + (long)t*SD;
        u16 spk[2];
        #pragma unroll
        for (int i=0;i<2;++i){
          int sl = s2 + i, sg = pj*16 + sl;
          float mean = pf[row*16+sl] + pf[512+row*16+sl] + pf[1024+row*16+sl] + pf[1536+row*16+sl];
          float rsv  = pf[256+row*16+sl] + pf[768+row*16+sl] + pf[1280+row*16+sl] + pf[1792+row*16+sl];
          mean += qe[sg];
          rsv  += qe[64+sg];
          float sp = fmaxf(rsv,0.f) + log1pf(expf(-fabsf(rsv)));
          float qs_ = sp + 1e-4f;
          float st = mean + ep[sg]*qs_;
          A.qm[grow*((long)TT*SD) + (long)t*SD + sg] = mean;
          A.qs[grow*((long)TT*SD) + (long)t*SD + sg] = qs_;
          spk[i] = f2bf(st);
        }
        uint32 pv; __builtin_memcpy(&pv, spk, 4);
        __hip_atomic_store((uint32*)(A.sto + grow*((long)TT*SD) + (long)t*SD + pj*16 + s2), pv,
                           __ATOMIC_RELAXED, __HIP_MEMORY_SCOPE_AGENT);
      }
      __syncthreads();
    }
    if (t+1 < TT) loadgt(t+1, 0);
    gsync_g(A.slots, m, n, (uint32)(2*t+2));
  }
}

// ================= fallback per-step kernels (round-2, tested) =================
__global__ __launch_bounds__(256) void gru_step(
    const u16* __restrict__ sto_prev, long ssto,
    const u16* __restrict__ act_t,
    const u16* __restrict__ det_prev, long sdet,
    const u16* __restrict__ Wih, const u16* __restrict__ Whh,
    const float* __restrict__ b_ih, const float* __restrict__ b_hh,
    float* __restrict__ deterF, u16* __restrict__ det_bf_t){
  constexpr int SA = 40;
  __shared__ u16 sA[32*SA];
  __shared__ u16 sB[96*SA];
  const int id = blockIdx.x;
  const int n = (id&7) + ((id>>7)<<3);
  const int m = (id>>3)&15;
  const int m0 = m*32, h0 = n*32;
  const int tid = threadIdx.x, lane = tid&63, wave = tid>>6;
  const int wm = wave>>1, wn = wave&1;
  const int lr = lane&15, kg = lane>>4;

  f32x4 aR = {}, aZ = {}, aNd = {}, aNx = {};

  auto aAddr = [&](int c, int row, int sc)->const u16*{
    if (c < 32) return det_prev + (long)(m0+row)*sdet + c*32 + sc;
    if (c < 34) return sto_prev + (long)(m0+row)*ssto + (c-32)*32 + sc;
    return act_t + (long)(m0+row)*((long)TT*ACTD) + sc;
  };
  auto bAddr = [&](int c, int l)->const u16*{
    int row = l>>2, sc = (l&3)*8;
    int g = row>>5, hr = row&31;
    if (c < 32) return Whh + (long)(g*1024 + h0 + hr)*HD + c*32 + sc;
    return Wih + (long)(g*1024 + h0 + hr)*(SD+ACTD) + (c-32)*32 + sc;
  };

  bf16x8 rA, rB0, rB1;
  auto loadc = [&](int c){
    rB0 = *(const bf16x8*)bAddr(c, tid);
    if (tid < 128){
      rA  = *(const bf16x8*)aAddr(c, tid>>2, (tid&3)*8);
      rB1 = *(const bf16x8*)bAddr(c, 256+tid);
    }
  };

  loadc(0);
  for (int c=0; c<35; ++c){
    *(bf16x8*)&sB[(tid>>2)*SA + (tid&3)*8] = rB0;
    if (tid < 128){
      *(bf16x8*)&sA[(tid>>2)*SA + (tid&3)*8] = rA;
      int l = 256+tid;
      *(bf16x8*)&sB[(l>>2)*SA + (l&3)*8] = rB1;
    }
    if (c < 34) loadc(c+1);
    __syncthreads();
    bf16x8 af = *(const bf16x8*)&sA[(wm*16+lr)*SA + kg*8];
    bf16x8 b0 = *(const bf16x8*)&sB[(     wn*16+lr)*SA + kg*8];
    bf16x8 b1 = *(const bf16x8*)&sB[(32 + wn*16+lr)*SA + kg*8];
    bf16x8 b2 = *(const bf16x8*)&sB[(64 + wn*16+lr)*SA + kg*8];
    aR = MFMA(af,b0,aR,0,0,0);
    aZ = MFMA(af,b1,aZ,0,0,0);
    if (c < 32) aNd = MFMA(af,b2,aNd,0,0,0);
    else        aNx = MFMA(af,b2,aNx,0,0,0);
    __syncthreads();
  }

  const int col = h0 + wn*16 + lr;
  const float bir = b_ih[col],      bhr = b_hh[col];
  const float biz = b_ih[col+HD],   bhz = b_hh[col+HD];
  const float bin = b_ih[col+2*HD], bhn = b_hh[col+2*HD];
  #pragma unroll
  for (int reg=0; reg<4; ++reg){
    const int row = m0 + wm*16 + kg*4 + reg;
    float r = sigm(aR[reg] + bir + bhr);
    float z = sigm(aZ[reg] + biz + bhz);
    float nn = tanhf(aNx[reg] + bin + r*(aNd[reg] + bhn));
    const long fidx = (long)row*HD + col;
    float d = (1.f - z)*nn + z*deterF[fidx];
    deterF[fidx] = d;
    det_bf_t[(long)row*STRD + col] = f2bf(d);
  }
}

__global__ __launch_bounds__(256) void post_step(
    const u16* __restrict__ det_t,
    const u16* __restrict__ Wpos,
    const float* __restrict__ qemb_t,
    const float* __restrict__ eps_t,
    float* __restrict__ qm_t, float* __restrict__ qs_t, u16* __restrict__ sto_out){
  constexpr int SA = 40;
  __shared__ u16 sA4[4*16*SA];
  __shared__ u16 sB4[4*128*SA];
  const int m0 = blockIdx.x*16;
  const int tid = threadIdx.x, lane = tid&63, w = tid>>6;
  const int lr = lane&15, kg = lane>>4;

  f32x4 acc[8] = {};
  bf16x8 rA, rB[8];
  auto loadIter = [&](int i){
    #pragma unroll
    for (int rnd=0; rnd<8; ++rnd){
      int l = rnd*256 + tid;
      int q = l>>9, row = (l>>2)&127, sc = (l&3)*8;
      rB[rnd] = *(const bf16x8*)(Wpos + (long)row*(2*HD) + (q*8+i)*32 + sc);
    }
    { int q = tid>>6, row = (tid>>2)&15, sc = (tid&3)*8;
      rA = *(const bf16x8*)(det_t + (long)(m0+row)*STRD + (q*8+i)*32 + sc); }
  };

  loadIter(0);
  for (int i=0; i<8; ++i){
    #pragma unroll
    for (int rnd=0; rnd<8; ++rnd){
      int l = rnd*256 + tid;
      int q = l>>9, row = (l>>2)&127, sc = (l&3)*8;
      *(bf16x8*)&sB4[q*128*SA + row*SA + sc] = rB[rnd];
    }
    { int q = tid>>6, row = (tid>>2)&15, sc = (tid&3)*8;
      *(bf16x8*)&sA4[q*16*SA + row*SA + sc] = rA; }
    if (i < 7) loadIter(i+1);
    __syncthreads();
    bf16x8 af = *(const bf16x8*)&sA4[w*16*SA + lr*SA + kg*8];
    #pragma unroll
    for (int j=0; j<8; ++j){
      bf16x8 bf = *(const bf16x8*)&sB4[w*128*SA + (j*16+lr)*SA + kg*8];
      acc[j] = MFMA(af, bf, acc[j], 0,0,0);
    }
    __syncthreads();
  }

  float* pf = (float*)sB4;
  #pragma unroll
  for (int j=0; j<8; ++j)
    #pragma unroll
    for (int reg=0; reg<4; ++reg)
      pf[w*2048 + (kg*4+reg)*128 + j*16+lr] = acc[j][reg];
  __syncthreads();

  #pragma unroll
  for (int i=0; i<4; ++i){
    int p = tid + i*256;
    int row = p>>6, s = p&63;
    int b = m0 + row;
    float mval = pf[row*128+s]      + pf[2048+row*128+s]      + pf[4096+row*128+s]      + pf[6144+row*128+s];
    float rsv  = pf[row*128+64+s]   + pf[2048+row*128+64+s]   + pf[4096+row*128+64+s]   + pf[6144+row*128+64+s];
    mval += qemb_t[(long)b*((long)TT*128) + s];
    rsv  += qemb_t[(long)b*((long)TT*128) + 64 + s];
    float sp = fmaxf(rsv,0.f) + log1pf(expf(-fabsf(rsv)));
    float qsv = sp + 1e-4f;
    float e = eps_t[(long)b*((long)TT*SD) + s];
    float st = mval + e*qsv;
    qm_t[(long)b*((long)TT*SD) + s] = mval;
    qs_t[(long)b*((long)TT*SD) + s] = qsv;
    sto_out[(long)b*((long)TT*SD) + s] = f2bf(st);
  }
}

// ---------- KL / heads ----------
__global__ void kl_kernel(const float* __restrict__ pbuf, const float* __restrict__ qm,
                          const float* __restrict__ qs, float* __restrict__ klrows){
  int m = blockIdx.x*4 + (threadIdx.x>>6);
  int s = threadIdx.x & 63;
  float pm   = pbuf[(long)m*128 + s];
  float praw = pbuf[(long)m*128 + 64 + s];
  float ps = fmaxf(praw,0.f) + log1pf(expf(-fabsf(praw))) + 1e-4f;
  float qmv = qm[(long)m*64+s], qsv = qs[(long)m*64+s];
  float d = qmv - pm;
  float kl = logf(ps/qsv) + (qsv*qsv + d*d)/(2.f*ps*ps) - 0.5f;
  #pragma unroll
  for (int off=32; off; off>>=1) kl += __shfl_xor(kl, off);
  if (s==0) klrows[m] = kl*(1.f/64.f);
}

__global__ void kl_reduce(const float* __restrict__ klrows, float* __restrict__ out){
  __shared__ float sm[256];
  float a = 0.f;
  for (int i=threadIdx.x; i<BT; i+=256) a += klrows[i];
  sm[threadIdx.x]=a; __syncthreads();
  for (int off=128; off; off>>=1){ if ((int)threadIdx.x<off) sm[threadIdx.x]+=sm[threadIdx.x+off]; __syncthreads(); }
  if (threadIdx.x==0) out[0] = sm[0] / (float)BT;
}

__global__ void rewdone_kernel(const u16* __restrict__ det, const u16* __restrict__ sto,
    const float* __restrict__ Wr, const float* __restrict__ br,
    const float* __restrict__ Wd, const float* __restrict__ bd,
    float* __restrict__ orew, float* __restrict__ odone){
  int m = blockIdx.x*4 + (threadIdx.x>>6);
  int lane = threadIdx.x & 63;
  float ar=0.f, ad=0.f;
  for (int k=lane; k<HD+SD; k+=64){
    float f = (k<HD) ? bf2f(det[(long)m*HD+k]) : bf2f(sto[(long)m*SD + (k-HD)]);
    ar = fmaf(f, Wr[k], ar); ad = fmaf(f, Wd[k], ad);
  }
  #pragma unroll
  for (int off=32; off; off>>=1){ ar += __shfl_xor(ar, off); ad += __shfl_xor(ad, off); }
  if (lane==0){ orew[m]=ar+br[0]; odone[m]=ad+bd[0]; }
}

static char* carve(char*& base, size_t bytes){
  char* p = base; base += (bytes + 255) & ~(size_t)255; return p;
}

extern "C" void kernel_launch(void* const* d_in, const int* in_sizes, int n_in,
                              void* d_out, int out_size, void* d_ws, size_t ws_size,
                              hipStream_t stream) {
  const float* obs    = (const float*)d_in[0];
  const float* action = (const float*)d_in[1];
  const float* eps    = (const float*)d_in[2];
  const float* W_enc  = (const float*)d_in[3];
  const float* b_enc  = (const float*)d_in[4];
  const float* W_ih   = (const float*)d_in[5];
  const float* W_hh   = (const float*)d_in[6];
  const float* b_ih   = (const float*)d_in[7];
  const float* b_hh   = (const float*)d_in[8];
  const float* W_prior= (const float*)d_in[9];
  const float* b_prior= (const float*)d_in[10];
  const float* W_post = (const float*)d_in[11];
  const float* b_post = (const float*)d_in[12];
  const float* W_dec1 = (const float*)d_in[13];
  const float* b_dec1 = (const float*)d_in[14];
  const float* W_dec2 = (const float*)d_in[15];
  const float* b_dec2 = (const float*)d_in[16];
  const float* W_rew  = (const float*)d_in[17];
  const float* b_rew  = (const float*)d_in[18];
  const float* W_done = (const float*)d_in[19];
  const float* b_done = (const float*)d_in[20];

  char* w = (char*)d_ws;
  u16* obs_bf  = (u16*)carve(w, (size_t)BT*OBSD*2);   // later reused as hid_bf
  u16* emb_bf  = (u16*)carve(w, (size_t)BT*HD*2);
  u16* det_bf  = (u16*)carve(w, (size_t)BT*HD*2);
  u16* sto_bf  = (u16*)carve(w, (size_t)BT*SD*2);
  u16* act_bf  = (u16*)carve(w, (size_t)BT*ACTD*2);
  u16* Wenc_bf = (u16*)carve(w, (size_t)HD*OBSD*2);
  u16* Wih_bf  = (u16*)carve(w, (size_t)G3*(SD+ACTD)*2);
  u16* Whh_bf  = (u16*)carve(w, (size_t)G3*HD*2);
  u16* Wpri_bf = (u16*)carve(w, (size_t)2*SD*HD*2);
  u16* Wpos_bf = (u16*)carve(w, (size_t)2*SD*2*HD*2);
  u16* Wd1_bf  = (u16*)carve(w, (size_t)HD*(HD+SD)*2);
  u16* Wd2_bf  = (u16*)carve(w, (size_t)OBSD*HD*2);
  u16* zero_bf = (u16*)carve(w, 4096);
  float* deterF = (float*)carve(w, (size_t)BB*HD*4);
  float* qemb   = (float*)carve(w, (size_t)BT*128*4);
  float* qm_all = (float*)carve(w, (size_t)BT*SD*4);
  float* qs_all = (float*)carve(w, (size_t)BT*SD*4);
  float* p_buf  = (float*)carve(w, (size_t)BT*2*SD*4);
  float* klrows = (float*)carve(w, (size_t)BT*4);
  uint32* syncb = (uint32*)carve(w, 8192);
  u16* hid_bf = obs_bf;

  if ((size_t)(w - (char*)d_ws) > ws_size){
    hipMemsetAsync(d_out, 0xFF, 4, stream);
    return;
  }

  auto cvt = [&](const float* in, u16* out, long n){
    cvt_kernel<<<dim3(2048), dim3(256), 0, stream>>>(in, out, n);
  };
  cvt(obs, obs_bf, (long)BT*OBSD);
  cvt(action, act_bf, (long)BT*ACTD);
  cvt(W_enc, Wenc_bf, (long)HD*OBSD);
  cvt(W_ih, Wih_bf, (long)G3*(SD+ACTD));
  cvt(W_hh, Whh_bf, (long)G3*HD);
  cvt(W_prior, Wpri_bf, (long)2*SD*HD);
  cvt(W_post, Wpos_bf, (long)2*SD*2*HD);
  cvt(W_dec1, Wd1_bf, (long)HD*(HD+SD));
  cvt(W_dec2, Wd2_bf, (long)OBSD*HD);
  hipMemsetAsync(zero_bf, 0, 4096, stream);
  hipMemsetAsync(deterF, 0, (size_t)BB*HD*4, stream);
  hipMemsetAsync(syncb, 0, 8192, stream);

  // ---- Phase 1a: encoder
  {
    GemmP q{};
    q.a0 = obs_bf;  q.lda0 = OBSD;
    q.b0 = Wenc_bf; q.ldb0 = OBSD;
    q.kc0=q.kc1=q.kc2=32; q.kcPerZ=32;
    q.cb = emb_bf; q.ldcb = HD;
    q.bias0 = b_enc; q.relu = 1;
    gemm_bf16<128,128><<<dim3(HD/128, BT/128, 1), 256, 0, stream>>>(q);
  }
  // ---- Phase 1b: Qemb
  {
    GemmP q{};
    q.a0 = emb_bf;       q.lda0 = HD;
    q.b0 = Wpos_bf + HD; q.ldb0 = 2*HD;
    q.kc0=q.kc1=q.kc2=32; q.kcPerZ=32;
    q.cf = qemb; q.ldc = 128;
    q.bias0 = b_post;
    gemm_bf16<64,64><<<dim3(128/64, BT/64, 1), 256, 0, stream>>>(q);
  }

  // ---- Phase 2: scan — coop 512 (2/CU) -> coop 256 (r11) -> per-step
  {
    ScanArgs sa;
    sa.act = act_bf; sa.Wih = Wih_bf; sa.Whh = Whh_bf;
    sa.b_ih = b_ih; sa.b_hh = b_hh;
    sa.Wpos = Wpos_bf; sa.qemb = qemb; sa.eps = eps;
    sa.det = det_bf; sa.sto = sto_bf; sa.qm = qm_all; sa.qs = qs_all;
    sa.slots = syncb; sa.zeroB = zero_bf;
    void* kargs[] = { (void*)&sa };
    hipError_t e1 = hipLaunchCooperativeKernel((const void*)scan_kernel32,
        dim3(512), dim3(256), kargs, 0, stream);
    if (e1 != hipSuccess){
      hipError_t e2 = hipLaunchCooperativeKernel((const void*)scan_kernel64,
          dim3(256), dim3(256), kargs, 0, stream);
      if (e2 != hipSuccess){
        for (int t=0; t<TT; ++t){
          const u16* sto_p = (t==0) ? zero_bf : (sto_bf + (long)(t-1)*SD);
          long ssto        = (t==0) ? 0 : (long)TT*SD;
          const u16* det_p = (t==0) ? zero_bf : (det_bf + (long)(t-1)*HD);
          long sdet        = (t==0) ? 0 : STRD;
          gru_step<<<dim3(512), 256, 0, stream>>>(sto_p, ssto, act_bf + (long)t*ACTD,
              det_p, sdet, Wih_bf, Whh_bf, b_ih, b_hh, deterF, det_bf + (long)t*HD);
          post_step<<<dim3(32), 256, 0, stream>>>(det_bf + (long)t*HD, Wpos_bf,
              qemb + (long)t*128, eps + (long)t*SD,
              qm_all + (long)t*SD, qs_all + (long)t*SD, sto_bf + (long)t*SD);
        }
      }
    }
  }

  // ---- Phase 3: batched heads ----
  {
    GemmP q{};
    q.a0 = det_bf;  q.lda0 = HD;
    q.b0 = Wpri_bf; q.ldb0 = HD;
    q.kc0=q.kc1=q.kc2=32; q.kcPerZ=32;
    q.cf = p_buf; q.ldc = 2*SD;
    q.bias0 = b_prior;
    gemm_bf16<64,64><<<dim3(2*SD/64, BT/64, 1), 256, 0, stream>>>(q);
  }
  kl_kernel<<<dim3(BT/4), 256, 0, stream>>>(p_buf, qm_all, qs_all, klrows);
  {
    GemmP q{};
    q.a0 = det_bf; q.lda0 = HD;
    q.a1 = sto_bf; q.lda1 = SD;
    q.b0 = Wd1_bf;      q.ldb0 = HD+SD;
    q.b1 = Wd1_bf + HD; q.ldb1 = HD+SD;
    q.kc0=32; q.kc1=34; q.kc2=34; q.kcPerZ=34;
    q.cb = hid_bf; q.ldcb = HD;
    q.bias0 = b_dec1; q.relu = 1;
    gemm_bf16<128,128><<<dim3(HD/128, BT/128, 1), 256, 0, stream>>>(q);
  }
  {
    GemmP q{};
    q.a0 = hid_bf; q.lda0 = HD;
    q.b0 = Wd2_bf; q.ldb0 = HD;
    q.kc0=q.kc1=q.kc2=32; q.kcPerZ=32;
    q.cf = (float*)d_out; q.ldc = OBSD;
    q.bias0 = b_dec2;
    gemm_bf16<128,128><<<dim3(OBSD/128, BT/128, 1), 256, 0, stream>>>(q);
  }
  rewdone_kernel<<<dim3(BT/4), 256, 0, stream>>>(det_bf, sto_bf, W_rew, b_rew, W_done, b_done,
      (float*)d_out + (long)BT*OBSD, (float*)d_out + (long)BT*OBSD + BT);
  kl_reduce<<<dim3(1), 256, 0, stream>>>(klrows, (float*)d_out + (long)BT*OBSD + 2*BT);
}

// Round 14
// 1659.962 us; speedup vs baseline: 2.1378x; 2.1378x over previous
//
#include <hip/hip_runtime.h>
#include <stdint.h>

#define BB 512
#define TT 64
#define OBSD 1024
#define ACTD 32
#define HD 1024
#define SD 64
#define BT (BB*TT)
#define G3 (3*HD)
#define STRD ((long)TT*HD)

typedef unsigned int uint32;
typedef unsigned long long ull;
typedef unsigned short u16;
typedef __attribute__((ext_vector_type(8))) short bf16x8;
typedef __attribute__((ext_vector_type(4))) float f32x4;

__device__ __forceinline__ float bf2f(u16 v){ uint32_t u = ((uint32_t)v)<<16; return __builtin_bit_cast(float,u); }
__device__ __forceinline__ u16 f2bf(float f){ uint32_t u = __builtin_bit_cast(uint32_t,f); uint32_t r = (u + 0x7FFFu + ((u>>16)&1u))>>16; return (u16)r; }
__device__ __forceinline__ float sigm(float x){ return 1.f/(1.f+expf(-x)); }
#define MFMA __builtin_amdgcn_mfma_f32_16x16x32_bf16

// width-16 async global->LDS (per-lane global src, wave-uniform LDS base + lane*16)
__device__ __forceinline__ void gload16(const u16* g, u16* l){
  __builtin_amdgcn_global_load_lds(
      (const __attribute__((address_space(1))) u16*)g,
      (__attribute__((address_space(3))) u16*)l, 16, 0, 0);
}

// ---------- f32 -> bf16 convert (RNE) ----------
__global__ void cvt_kernel(const float* __restrict__ in, u16* __restrict__ out, long n){
  long i = (long)blockIdx.x*blockDim.x + threadIdx.x;
  long st = (long)gridDim.x*blockDim.x;
  for (; i<n; i+=st) out[i] = f2bf(in[i]);
}

// ---------- generic bf16 MFMA GEMM (r11, gload_lds dbuf, tested) ----------
struct GemmP {
  const u16* a0; const u16* a1; const u16* a2;
  const u16* b0; const u16* b1; const u16* b2;
  long lda0, lda1, lda2, ldb0, ldb1, ldb2;
  int kc0, kc1, kc2, kcPerZ;
  float* cf; u16* cb;
  long ldc, ldcb, zstride;
  const float* bias0; const float* bias1;
  int relu;
};

template<int BM,int BN>
__global__ __launch_bounds__(256) void gemm_bf16(GemmP p){
  __shared__ __align__(16) u16 sAB[2][(BM+BN)*32];
  const int m0 = blockIdx.y*BM, n0 = blockIdx.x*BN;
  const int tid = threadIdx.x, lane = tid&63, wave = tid>>6;
  const int wm = (wave>>1)*(BM/2), wn = (wave&1)*(BN/2);
  constexpr int FM = BM/32, FN = BN/32;
  f32x4 acc[FM][FN] = {};
  const int cbeg = blockIdx.z*p.kcPerZ;
  int cend = cbeg + p.kcPerZ; if (cend > p.kc2) cend = p.kc2;
  const int kg = lane>>4, lr = lane&15;
  const int srow = lane>>2, scol = (lane&3)*8;

  auto STAGE = [&](int buf, int c){
    const u16* ap; const u16* bp; long lda, ldb; int kofs;
    if (c < p.kc0){ ap=p.a0; bp=p.b0; lda=p.lda0; ldb=p.ldb0; kofs=c*32; }
    else if (c < p.kc1){ ap=p.a1; bp=p.b1; lda=p.lda1; ldb=p.ldb1; kofs=(c-p.kc0)*32; }
    else { ap=p.a2; bp=p.b2; lda=p.lda2; ldb=p.ldb2; kofs=(c-p.kc1)*32; }
    u16* base = sAB[buf];
    #pragma unroll
    for (int it=0; it<BM/64; ++it){
      int row = it*64 + wave*16 + srow;
      gload16(ap + (long)(m0+row)*lda + kofs + scol,
              base + (it*64 + wave*16)*32);
    }
    #pragma unroll
    for (int it=0; it<BN/64; ++it){
      int row = it*64 + wave*16 + srow;
      gload16(bp + (long)(n0+row)*ldb + kofs + scol,
              base + BM*32 + (it*64 + wave*16)*32);
    }
  };

  STAGE(0, cbeg);
  for (int c=cbeg;c<cend;++c){
    const int cur = (c-cbeg)&1;
    asm volatile("s_waitcnt vmcnt(0)" ::: "memory");
    __syncthreads();
    if (c+1 < cend) STAGE(cur^1, c+1);
    const u16* sA = sAB[cur];
    const u16* sB = sAB[cur] + BM*32;
    bf16x8 af[FM], bfv[FN];
    #pragma unroll
    for (int i=0;i<FM;++i) af[i] = *(const bf16x8*)&sA[(wm+i*16+lr)*32 + kg*8];
    #pragma unroll
    for (int j=0;j<FN;++j) bfv[j] = *(const bf16x8*)&sB[(wn+j*16+lr)*32 + kg*8];
    #pragma unroll
    for (int i=0;i<FM;++i)
      #pragma unroll
      for (int j=0;j<FN;++j)
        acc[i][j] = MFMA(af[i], bfv[j], acc[i][j], 0,0,0);
    __syncthreads();
  }
  const bool partial = (gridDim.z > 1);
  float* cf = p.cf ? (p.cf + (partial ? (long)blockIdx.z*p.zstride : 0)) : nullptr;
  #pragma unroll
  for (int i=0;i<FM;++i){
    #pragma unroll
    for (int j=0;j<FN;++j){
      const int gr0 = m0 + wm + i*16 + kg*4;
      const int gc = n0 + wn + j*16 + lr;
      float bias = 0.f;
      if (!partial){
        if (p.bias0) bias += p.bias0[gc];
        if (p.bias1) bias += p.bias1[gc];
      }
      #pragma unroll
      for (int r=0;r<4;++r){
        float v = acc[i][j][r] + bias;
        if (p.relu) v = fmaxf(v, 0.f);
        const long row = gr0 + r;
        if (cf) cf[row*p.ldc + gc] = v;
        if (p.cb) p.cb[row*p.ldcb + gc] = f2bf(v);
      }
    }
  }
}

// ================= persistent cooperative scan (256 blocks, 1/CU) =================
struct ScanArgs {
  const u16* act; const u16* Wih; const u16* Whh;
  const float* b_ih; const float* b_hh;
  const u16* Wpos; const float* qemb; const float* eps;
  u16* det; u16* sto; float* qm; float* qs;
  uint32* slots; const u16* zeroB;
};

// Group-local (32-block) arrive-by-store barrier (r9-proven primitive).
__device__ __forceinline__ void gsync_g(uint32* slots, int m, int n, uint32 val){
  asm volatile("s_waitcnt vmcnt(0)" ::: "memory");
  __syncthreads();
  if (threadIdx.x == 0)
    __hip_atomic_store(&slots[m*64 + n], val, __ATOMIC_RELAXED, __HIP_MEMORY_SCOPE_AGENT);
  if (threadIdx.x < 32){
    while (__hip_atomic_load(&slots[m*64 + threadIdx.x], __ATOMIC_RELAXED,
                             __HIP_MEMORY_SCOPE_AGENT) < val)
      __builtin_amdgcn_s_sleep(2);
  }
  __syncthreads();
}

#define SA2 152   // 304B row stride

__global__ __launch_bounds__(256, 1) void scan_kernel(ScanArgs A){
  __shared__ __align__(16) u16 lds[(64+96)*SA2];
  u16* sA = lds; u16* sB = lds + 64*SA2;
  float* pf = (float*)lds;
  const int bid = blockIdx.x;
  const int tid = threadIdx.x, lane = tid&63, wave = tid>>6;
  const int lr = lane&15, kg = lane>>4;
  const int n = bid&31, m = bid>>5;       // n%8 -> XCD: W-slices L2-resident
  const int m0 = m*64, h0 = n*32;
  const int wrow = (wave&1)*32, wcol = (wave>>1)*16;

  const int srow = tid>>4;          // 0..15
  const int scu  = (tid&15)*8;      // 0..120

  long whhb[6], wihb[6];
  #pragma unroll
  for (int i=0;i<6;++i){
    int br = srow + i*16;           // 0..95
    int gate = br>>5, hr = br&31;
    whhb[i] = (long)(gate*HD + h0 + hr)*HD + scu;
    wihb[i] = (long)(gate*HD + h0 + hr)*96 + scu;
  }

  // swapped-operand C layout: lane owns batch row (lr) x 4 consecutive h (kg*4+reg)
  const int h4 = h0 + wcol + kg*4;
  float bir[4], bhr[4], biz[4], bhz[4], bin[4], bhn[4];
  #pragma unroll
  for (int r=0;r<4;++r){
    bir[r]=A.b_ih[h4+r];      bhr[r]=A.b_hh[h4+r];
    biz[r]=A.b_ih[HD+h4+r];   bhz[r]=A.b_hh[HD+h4+r];
    bin[r]=A.b_ih[2*HD+h4+r]; bhn[r]=A.b_hh[2*HD+h4+r];
  }

  // distributed posterior tile: s-tile pj (16 s), row-tile prt (8 rows)
  const int pj = n & 3, prt = n >> 2;

  float dreg[2][4] = {{0.f,0.f,0.f,0.f},{0.f,0.f,0.f,0.f}};
  const bf16x8 zerov = {};

  // depth-3 register queue for A-fragments (det/sto/act); B single-depth (L2-hot)
  bf16x8 paQ[3][4], pb[6];
  auto loadA = [&](int tt, int g, bf16x8 (&dst)[4]){
    if (g < 8){
      if (tt > 0){
        const u16* s = A.det + (long)(tt-1)*HD + g*128 + scu;
        #pragma unroll
        for (int j=0;j<4;++j) dst[j] = *(const bf16x8*)(s + (long)(m0+srow+16*j)*STRD);
      } else { dst[0]=zerov; dst[1]=zerov; dst[2]=zerov; dst[3]=zerov; }
    } else {
      if (scu < 64){
        if (tt > 0){
          #pragma unroll
          for (int j=0;j<4;++j)
            dst[j] = *(const bf16x8*)(A.sto + (long)(m0+srow+16*j)*((long)TT*SD) + (long)(tt-1)*SD + scu);
        } else { dst[0]=zerov; dst[1]=zerov; dst[2]=zerov; dst[3]=zerov; }
      } else if (scu < 96){
        #pragma unroll
        for (int j=0;j<4;++j)
          dst[j] = *(const bf16x8*)(A.act + (long)(m0+srow+16*j)*((long)TT*ACTD) + (long)tt*ACTD + (scu-64));
      } else { dst[0]=zerov; dst[1]=zerov; dst[2]=zerov; dst[3]=zerov; }
    }
  };
  auto loadB = [&](int g){
    if (g < 8){
      #pragma unroll
      for (int i=0;i<6;++i) pb[i] = *(const bf16x8*)(A.Whh + whhb[i] + g*128);
    } else {
      #pragma unroll
      for (int i=0;i<6;++i) pb[i] = (scu < 96) ? *(const bf16x8*)(A.Wih + wihb[i]) : zerov;
    }
  };

  loadA(0, 0, paQ[0]); loadA(0, 1, paQ[1]); loadA(0, 2, paQ[2]); loadB(0);

  for (int t=0; t<TT; ++t){
    // ---------------- gates GEMM (9 K-groups of 128), depth-3 A pipeline ----------------
    f32x4 aR[2]={}, aZ[2]={}, aNd[2]={}, aNx[2]={};
    #pragma unroll
    for (int g=0; g<9; ++g){
      __syncthreads();
      #pragma unroll
      for (int j=0;j<4;++j) *(bf16x8*)&sA[(srow+16*j)*SA2 + scu] = paQ[g%3][j];
      #pragma unroll
      for (int i=0;i<6;++i) *(bf16x8*)&sB[(srow+16*i)*SA2 + scu] = pb[i];
      if (g < 8) loadB(g+1);
      if (g+3 <= 8) loadA(t, g+3, paQ[(g+3)%3]);
      __syncthreads();
      #pragma unroll
      for (int k=0;k<4;++k){
        bf16x8 a0v = *(const bf16x8*)&sA[(wrow+lr)*SA2 + k*32 + kg*8];
        bf16x8 a1v = *(const bf16x8*)&sA[(wrow+16+lr)*SA2 + k*32 + kg*8];
        bf16x8 b0 = *(const bf16x8*)&sB[(wcol+lr)*SA2 + k*32 + kg*8];
        bf16x8 b1 = *(const bf16x8*)&sB[(32+wcol+lr)*SA2 + k*32 + kg*8];
        bf16x8 b2 = *(const bf16x8*)&sB[(64+wcol+lr)*SA2 + k*32 + kg*8];
        // swapped operands: C row-axis (kg*4+reg) = h, col-axis (lane&15) = batch
        aR[0] = MFMA(b0,a0v,aR[0],0,0,0); aR[1] = MFMA(b0,a1v,aR[1],0,0,0);
        aZ[0] = MFMA(b1,a0v,aZ[0],0,0,0); aZ[1] = MFMA(b1,a1v,aZ[1],0,0,0);
        if (g<8){ aNd[0] = MFMA(b2,a0v,aNd[0],0,0,0); aNd[1] = MFMA(b2,a1v,aNd[1],0,0,0); }
        else    { aNx[0] = MFMA(b2,a0v,aNx[0],0,0,0); aNx[1] = MFMA(b2,a1v,aNx[1],0,0,0); }
      }
    }
    // GRU epilogue; det written write-through (8B granules)
    #pragma unroll
    for (int rf=0;rf<2;++rf){
      const long brow = m0 + wrow + rf*16 + lr;
      u16 pk[4];
      #pragma unroll
      for (int r=0;r<4;++r){
        float rr = sigm(aR[rf][r]+bir[r]+bhr[r]);
        float z  = sigm(aZ[rf][r]+biz[r]+bhz[r]);
        float nn = tanhf(aNx[rf][r]+bin[r] + rr*(aNd[rf][r]+bhn[r]));
        float d = (1.f - z)*nn + z*dreg[rf][r];
        dreg[rf][r] = d;
        pk[r] = f2bf(d);
      }
      ull pv; __builtin_memcpy(&pv, pk, 8);
      __hip_atomic_store((ull*)(A.det + brow*STRD + (long)t*HD + h4), pv,
                         __ATOMIC_RELAXED, __HIP_MEMORY_SCOPE_AGENT);
    }
    gsync_g(A.slots, m, n, (uint32)(2*t+1));

    // ---------------- distributed posterior: 8 rows x (16 mean + 16 std) ----------------
    {
      f32x4 accM = {}, accS = {};
      const int k0 = wave*256;
      const u16* arow = A.det + (long)(m0 + prt*8 + (lr&7))*STRD + (long)t*HD + k0 + kg*8;
      const u16* bm = A.Wpos + (long)(pj*16 + lr)*(2*HD) + k0 + kg*8;
      const u16* bs = A.Wpos + (long)(64 + pj*16 + lr)*(2*HD) + k0 + kg*8;
      #pragma unroll
      for (int kk=0; kk<8; ++kk){
        bf16x8 af = *(const bf16x8*)(arow + kk*32);
        accM = MFMA(af, *(const bf16x8*)(bm + kk*32), accM, 0,0,0);
        accS = MFMA(af, *(const bf16x8*)(bs + kk*32), accS, 0,0,0);
      }
      #pragma unroll
      for (int r=0;r<4;++r){
        int rowt = kg*4 + r;
        pf[wave*512 + rowt*16 + lr]       = accM[r];
        pf[wave*512 + 256 + rowt*16 + lr] = accS[r];
      }
      __syncthreads();
      if (tid < 64){
        const int row = tid>>3;        // 0..7 (C rows 8..15 are duplicates)
        const int s2 = (tid&7)*2;
        const long grow = m0 + prt*8 + row;
        const float* qe = A.qemb + grow*((long)TT*128) + (long)t*128;
        const float* ep = A.eps  + grow*((long)TT*SD) + (long)t*SD;
        u16 spk[2];
        #pragma unroll
        for (int i=0;i<2;++i){
          int sl = s2 + i, sg = pj*16 + sl;
          float mean = pf[row*16+sl] + pf[512+row*16+sl] + pf[1024+row*16+sl] + pf[1536+row*16+sl];
          float rsv  = pf[256+row*16+sl] + pf[768+row*16+sl] + pf[1280+row*16+sl] + pf[1792+row*16+sl];
          mean += qe[sg];
          rsv  += qe[64+sg];
          float sp = fmaxf(rsv,0.f) + log1pf(expf(-fabsf(rsv)));
          float qs_ = sp + 1e-4f;
          float st = mean + ep[sg]*qs_;
          A.qm[grow*((long)TT*SD) + (long)t*SD + sg] = mean;
          A.qs[grow*((long)TT*SD) + (long)t*SD + sg] = qs_;
          spk[i] = f2bf(st);
        }
        uint32 pv; __builtin_memcpy(&pv, spk, 4);
        __hip_atomic_store((uint32*)(A.sto + grow*((long)TT*SD) + (long)t*SD + pj*16 + s2), pv,
                           __ATOMIC_RELAXED, __HIP_MEMORY_SCOPE_AGENT);
      }
      __syncthreads();
    }
    // prefetch next step's gates groups 0..2 (det(t) ready after barrier 1);
    // their MALL latency overlaps the barrier-2 wait.
    if (t+1 < TT){
      loadA(t+1, 0, paQ[0]);
      loadA(t+1, 1, paQ[1]);
      loadA(t+1, 2, paQ[2]);
      loadB(0);
    }
    gsync_g(A.slots, m, n, (uint32)(2*t+2));
  }
}

// ================= fallback per-step kernels (round-2, tested) =================
__global__ __launch_bounds__(256) void gru_step(
    const u16* __restrict__ sto_prev, long ssto,
    const u16* __restrict__ act_t,
    const u16* __restrict__ det_prev, long sdet,
    const u16* __restrict__ Wih, const u16* __restrict__ Whh,
    const float* __restrict__ b_ih, const float* __restrict__ b_hh,
    float* __restrict__ deterF, u16* __restrict__ det_bf_t){
  constexpr int SA = 40;
  __shared__ u16 sA[32*SA];
  __shared__ u16 sB[96*SA];
  const int id = blockIdx.x;
  const int n = (id&7) + ((id>>7)<<3);
  const int m = (id>>3)&15;
  const int m0 = m*32, h0 = n*32;
  const int tid = threadIdx.x, lane = tid&63, wave = tid>>6;
  const int wm = wave>>1, wn = wave&1;
  const int lr = lane&15, kg = lane>>4;

  f32x4 aR = {}, aZ = {}, aNd = {}, aNx = {};

  auto aAddr = [&](int c, int row, int sc)->const u16*{
    if (c < 32) return det_prev + (long)(m0+row)*sdet + c*32 + sc;
    if (c < 34) return sto_prev + (long)(m0+row)*ssto + (c-32)*32 + sc;
    return act_t + (long)(m0+row)*((long)TT*ACTD) + sc;
  };
  auto bAddr = [&](int c, int l)->const u16*{
    int row = l>>2, sc = (l&3)*8;
    int g = row>>5, hr = row&31;
    if (c < 32) return Whh + (long)(g*1024 + h0 + hr)*HD + c*32 + sc;
    return Wih + (long)(g*1024 + h0 + hr)*(SD+ACTD) + (c-32)*32 + sc;
  };

  bf16x8 rA, rB0, rB1;
  auto loadc = [&](int c){
    rB0 = *(const bf16x8*)bAddr(c, tid);
    if (tid < 128){
      rA  = *(const bf16x8*)aAddr(c, tid>>2, (tid&3)*8);
      rB1 = *(const bf16x8*)bAddr(c, 256+tid);
    }
  };

  loadc(0);
  for (int c=0; c<35; ++c){
    *(bf16x8*)&sB[(tid>>2)*SA + (tid&3)*8] = rB0;
    if (tid < 128){
      *(bf16x8*)&sA[(tid>>2)*SA + (tid&3)*8] = rA;
      int l = 256+tid;
      *(bf16x8*)&sB[(l>>2)*SA + (l&3)*8] = rB1;
    }
    if (c < 34) loadc(c+1);
    __syncthreads();
    bf16x8 af = *(const bf16x8*)&sA[(wm*16+lr)*SA + kg*8];
    bf16x8 b0 = *(const bf16x8*)&sB[(     wn*16+lr)*SA + kg*8];
    bf16x8 b1 = *(const bf16x8*)&sB[(32 + wn*16+lr)*SA + kg*8];
    bf16x8 b2 = *(const bf16x8*)&sB[(64 + wn*16+lr)*SA + kg*8];
    aR = MFMA(af,b0,aR,0,0,0);
    aZ = MFMA(af,b1,aZ,0,0,0);
    if (c < 32) aNd = MFMA(af,b2,aNd,0,0,0);
    else        aNx = MFMA(af,b2,aNx,0,0,0);
    __syncthreads();
  }

  const int col = h0 + wn*16 + lr;
  const float bir = b_ih[col],      bhr = b_hh[col];
  const float biz = b_ih[col+HD],   bhz = b_hh[col+HD];
  const float bin = b_ih[col+2*HD], bhn = b_hh[col+2*HD];
  #pragma unroll
  for (int reg=0; reg<4; ++reg){
    const int row = m0 + wm*16 + kg*4 + reg;
    float r = sigm(aR[reg] + bir + bhr);
    float z = sigm(aZ[reg] + biz + bhz);
    float nn = tanhf(aNx[reg] + bin + r*(aNd[reg] + bhn));
    const long fidx = (long)row*HD + col;
    float d = (1.f - z)*nn + z*deterF[fidx];
    deterF[fidx] = d;
    det_bf_t[(long)row*STRD + col] = f2bf(d);
  }
}

__global__ __launch_bounds__(256) void post_step(
    const u16* __restrict__ det_t,
    const u16* __restrict__ Wpos,
    const float* __restrict__ qemb_t,
    const float* __restrict__ eps_t,
    float* __restrict__ qm_t, float* __restrict__ qs_t, u16* __restrict__ sto_out){
  constexpr int SA = 40;
  __shared__ u16 sA4[4*16*SA];
  __shared__ u16 sB4[4*128*SA];
  const int m0 = blockIdx.x*16;
  const int tid = threadIdx.x, lane = tid&63, w = tid>>6;
  const int lr = lane&15, kg = lane>>4;

  f32x4 acc[8] = {};
  bf16x8 rA, rB[8];
  auto loadIter = [&](int i){
    #pragma unroll
    for (int rnd=0; rnd<8; ++rnd){
      int l = rnd*256 + tid;
      int q = l>>9, row = (l>>2)&127, sc = (l&3)*8;
      rB[rnd] = *(const bf16x8*)(Wpos + (long)row*(2*HD) + (q*8+i)*32 + sc);
    }
    { int q = tid>>6, row = (tid>>2)&15, sc = (tid&3)*8;
      rA = *(const bf16x8*)(det_t + (long)(m0+row)*STRD + (q*8+i)*32 + sc); }
  };

  loadIter(0);
  for (int i=0; i<8; ++i){
    #pragma unroll
    for (int rnd=0; rnd<8; ++rnd){
      int l = rnd*256 + tid;
      int q = l>>9, row = (l>>2)&127, sc = (l&3)*8;
      *(bf16x8*)&sB4[q*128*SA + row*SA + sc] = rB[rnd];
    }
    { int q = tid>>6, row = (tid>>2)&15, sc = (tid&3)*8;
      *(bf16x8*)&sA4[q*16*SA + row*SA + sc] = rA; }
    if (i < 7) loadIter(i+1);
    __syncthreads();
    bf16x8 af = *(const bf16x8*)&sA4[w*16*SA + lr*SA + kg*8];
    #pragma unroll
    for (int j=0; j<8; ++j){
      bf16x8 bf = *(const bf16x8*)&sB4[w*128*SA + (j*16+lr)*SA + kg*8];
      acc[j] = MFMA(af, bf, acc[j], 0,0,0);
    }
    __syncthreads();
  }

  float* pf = (float*)sB4;
  #pragma unroll
  for (int j=0; j<8; ++j)
    #pragma unroll
    for (int reg=0; reg<4; ++reg)
      pf[w*2048 + (kg*4+reg)*128 + j*16+lr] = acc[j][reg];
  __syncthreads();

  #pragma unroll
  for (int i=0; i<4; ++i){
    int p = tid + i*256;
    int row = p>>6, s = p&63;
    int b = m0 + row;
    float mval = pf[row*128+s]      + pf[2048+row*128+s]      + pf[4096+row*128+s]      + pf[6144+row*128+s];
    float rsv  = pf[row*128+64+s]   + pf[2048+row*128+64+s]   + pf[4096+row*128+64+s]   + pf[6144+row*128+64+s];
    mval += qemb_t[(long)b*((long)TT*128) + s];
    rsv  += qemb_t[(long)b*((long)TT*128) + 64 + s];
    float sp = fmaxf(rsv,0.f) + log1pf(expf(-fabsf(rsv)));
    float qsv = sp + 1e-4f;
    float e = eps_t[(long)b*((long)TT*SD) + s];
    float st = mval + e*qsv;
    qm_t[(long)b*((long)TT*SD) + s] = mval;
    qs_t[(long)b*((long)TT*SD) + s] = qsv;
    sto_out[(long)b*((long)TT*SD) + s] = f2bf(st);
  }
}

// ---------- KL / heads ----------
__global__ void kl_kernel(const float* __restrict__ pbuf, const float* __restrict__ qm,
                          const float* __restrict__ qs, float* __restrict__ klrows){
  int m = blockIdx.x*4 + (threadIdx.x>>6);
  int s = threadIdx.x & 63;
  float pm   = pbuf[(long)m*128 + s];
  float praw = pbuf[(long)m*128 + 64 + s];
  float ps = fmaxf(praw,0.f) + log1pf(expf(-fabsf(praw))) + 1e-4f;
  float qmv = qm[(long)m*64+s], qsv = qs[(long)m*64+s];
  float d = qmv - pm;
  float kl = logf(ps/qsv) + (qsv*qsv + d*d)/(2.f*ps*ps) - 0.5f;
  #pragma unroll
  for (int off=32; off; off>>=1) kl += __shfl_xor(kl, off);
  if (s==0) klrows[m] = kl*(1.f/64.f);
}

__global__ void kl_reduce(const float* __restrict__ klrows, float* __restrict__ out){
  __shared__ float sm[256];
  float a = 0.f;
  for (int i=threadIdx.x; i<BT; i+=256) a += klrows[i];
  sm[threadIdx.x]=a; __syncthreads();
  for (int off=128; off; off>>=1){ if ((int)threadIdx.x<off) sm[threadIdx.x]+=sm[threadIdx.x+off]; __syncthreads(); }
  if (threadIdx.x==0) out[0] = sm[0] / (float)BT;
}

__global__ void rewdone_kernel(const u16* __restrict__ det, const u16* __restrict__ sto,
    const float* __restrict__ Wr, const float* __restrict__ br,
    const float* __restrict__ Wd, const float* __restrict__ bd,
    float* __restrict__ orew, float* __restrict__ odone){
  int m = blockIdx.x*4 + (threadIdx.x>>6);
  int lane = threadIdx.x & 63;
  float ar=0.f, ad=0.f;
  for (int k=lane; k<HD+SD; k+=64){
    float f = (k<HD) ? bf2f(det[(long)m*HD+k]) : bf2f(sto[(long)m*SD + (k-HD)]);
    ar = fmaf(f, Wr[k], ar); ad = fmaf(f, Wd[k], ad);
  }
  #pragma unroll
  for (int off=32; off; off>>=1){ ar += __shfl_xor(ar, off); ad += __shfl_xor(ad, off); }
  if (lane==0){ orew[m]=ar+br[0]; odone[m]=ad+bd[0]; }
}

static char* carve(char*& base, size_t bytes){
  char* p = base; base += (bytes + 255) & ~(size_t)255; return p;
}

extern "C" void kernel_launch(void* const* d_in, const int* in_sizes, int n_in,
                              void* d_out, int out_size, void* d_ws, size_t ws_size,
                              hipStream_t stream) {
  const float* obs    = (const float*)d_in[0];
  const float* action = (const float*)d_in[1];
  const float* eps    = (const float*)d_in[2];
  const float* W_enc  = (const float*)d_in[3];
  const float* b_enc  = (const float*)d_in[4];
  const float* W_ih   = (const float*)d_in[5];
  const float* W_hh   = (const float*)d_in[6];
  const float* b_ih   = (const float*)d_in[7];
  const float* b_hh   = (const float*)d_in[8];
  const float* W_prior= (const float*)d_in[9];
  const float* b_prior= (const float*)d_in[10];
  const float* W_post = (const float*)d_in[11];
  const float* b_post = (const float*)d_in[12];
  const float* W_dec1 = (const float*)d_in[13];
  const float* b_dec1 = (const float*)d_in[14];
  const float* W_dec2 = (const float*)d_in[15];
  const float* b_dec2 = (const float*)d_in[16];
  const float* W_rew  = (const float*)d_in[17];
  const float* b_rew  = (const float*)d_in[18];
  const float* W_done = (const float*)d_in[19];
  const float* b_done = (const float*)d_in[20];

  char* w = (char*)d_ws;
  u16* obs_bf  = (u16*)carve(w, (size_t)BT*OBSD*2);   // later reused as hid_bf
  u16* emb_bf  = (u16*)carve(w, (size_t)BT*HD*2);
  u16* det_bf  = (u16*)carve(w, (size_t)BT*HD*2);
  u16* sto_bf  = (u16*)carve(w, (size_t)BT*SD*2);
  u16* act_bf  = (u16*)carve(w, (size_t)BT*ACTD*2);
  u16* Wenc_bf = (u16*)carve(w, (size_t)HD*OBSD*2);
  u16* Wih_bf  = (u16*)carve(w, (size_t)G3*(SD+ACTD)*2);
  u16* Whh_bf  = (u16*)carve(w, (size_t)G3*HD*2);
  u16* Wpri_bf = (u16*)carve(w, (size_t)2*SD*HD*2);
  u16* Wpos_bf = (u16*)carve(w, (size_t)2*SD*2*HD*2);
  u16* Wd1_bf  = (u16*)carve(w, (size_t)HD*(HD+SD)*2);
  u16* Wd2_bf  = (u16*)carve(w, (size_t)OBSD*HD*2);
  u16* zero_bf = (u16*)carve(w, 4096);
  float* deterF = (float*)carve(w, (size_t)BB*HD*4);
  float* qemb   = (float*)carve(w, (size_t)BT*128*4);
  float* qm_all = (float*)carve(w, (size_t)BT*SD*4);
  float* qs_all = (float*)carve(w, (size_t)BT*SD*4);
  float* p_buf  = (float*)carve(w, (size_t)BT*2*SD*4);
  float* klrows = (float*)carve(w, (size_t)BT*4);
  uint32* syncb = (uint32*)carve(w, 8192);
  u16* hid_bf = obs_bf;

  if ((size_t)(w - (char*)d_ws) > ws_size){
    hipMemsetAsync(d_out, 0xFF, 4, stream);
    return;
  }

  auto cvt = [&](const float* in, u16* out, long n){
    cvt_kernel<<<dim3(2048), dim3(256), 0, stream>>>(in, out, n);
  };
  cvt(obs, obs_bf, (long)BT*OBSD);
  cvt(action, act_bf, (long)BT*ACTD);
  cvt(W_enc, Wenc_bf, (long)HD*OBSD);
  cvt(W_ih, Wih_bf, (long)G3*(SD+ACTD));
  cvt(W_hh, Whh_bf, (long)G3*HD);
  cvt(W_prior, Wpri_bf, (long)2*SD*HD);
  cvt(W_post, Wpos_bf, (long)2*SD*2*HD);
  cvt(W_dec1, Wd1_bf, (long)HD*(HD+SD));
  cvt(W_dec2, Wd2_bf, (long)OBSD*HD);
  hipMemsetAsync(zero_bf, 0, 4096, stream);
  hipMemsetAsync(deterF, 0, (size_t)BB*HD*4, stream);
  hipMemsetAsync(syncb, 0, 8192, stream);

  // ---- Phase 1a: encoder
  {
    GemmP q{};
    q.a0 = obs_bf;  q.lda0 = OBSD;
    q.b0 = Wenc_bf; q.ldb0 = OBSD;
    q.kc0=q.kc1=q.kc2=32; q.kcPerZ=32;
    q.cb = emb_bf; q.ldcb = HD;
    q.bias0 = b_enc; q.relu = 1;
    gemm_bf16<128,128><<<dim3(HD/128, BT/128, 1), 256, 0, stream>>>(q);
  }
  // ---- Phase 1b: Qemb
  {
    GemmP q{};
    q.a0 = emb_bf;       q.lda0 = HD;
    q.b0 = Wpos_bf + HD; q.ldb0 = 2*HD;
    q.kc0=q.kc1=q.kc2=32; q.kcPerZ=32;
    q.cf = qemb; q.ldc = 128;
    q.bias0 = b_post;
    gemm_bf16<64,64><<<dim3(128/64, BT/64, 1), 256, 0, stream>>>(q);
  }

  // ---- Phase 2: cooperative persistent scan (256 blocks), fallback to per-step
  {
    ScanArgs sa;
    sa.act = act_bf; sa.Wih = Wih_bf; sa.Whh = Whh_bf;
    sa.b_ih = b_ih; sa.b_hh = b_hh;
    sa.Wpos = Wpos_bf; sa.qemb = qemb; sa.eps = eps;
    sa.det = det_bf; sa.sto = sto_bf; sa.qm = qm_all; sa.qs = qs_all;
    sa.slots = syncb; sa.zeroB = zero_bf;
    void* kargs[] = { (void*)&sa };
    hipError_t cerr = hipLaunchCooperativeKernel((const void*)scan_kernel,
        dim3(256), dim3(256), kargs, 0, stream);
    if (cerr != hipSuccess){
      for (int t=0; t<TT; ++t){
        const u16* sto_p = (t==0) ? zero_bf : (sto_bf + (long)(t-1)*SD);
        long ssto        = (t==0) ? 0 : (long)TT*SD;
        const u16* det_p = (t==0) ? zero_bf : (det_bf + (long)(t-1)*HD);
        long sdet        = (t==0) ? 0 : STRD;
        gru_step<<<dim3(512), 256, 0, stream>>>(sto_p, ssto, act_bf + (long)t*ACTD,
            det_p, sdet, Wih_bf, Whh_bf, b_ih, b_hh, deterF, det_bf + (long)t*HD);
        post_step<<<dim3(32), 256, 0, stream>>>(det_bf + (long)t*HD, Wpos_bf,
            qemb + (long)t*128, eps + (long)t*SD,
            qm_all + (long)t*SD, qs_all + (long)t*SD, sto_bf + (long)t*SD);
      }
    }
  }

  // ---- Phase 3: batched heads ----
  {
    GemmP q{};
    q.a0 = det_bf;  q.lda0 = HD;
    q.b0 = Wpri_bf; q.ldb0 = HD;
    q.kc0=q.kc1=q.kc2=32; q.kcPerZ=32;
    q.cf = p_buf; q.ldc = 2*SD;
    q.bias0 = b_prior;
    gemm_bf16<64,64><<<dim3(2*SD/64, BT/64, 1), 256, 0, stream>>>(q);
  }
  kl_kernel<<<dim3(BT/4), 256, 0, stream>>>(p_buf, qm_all, qs_all, klrows);
  {
    GemmP q{};
    q.a0 = det_bf; q.lda0 = HD;
    q.a1 = sto_bf; q.lda1 = SD;
    q.b0 = Wd1_bf;      q.ldb0 = HD+SD;
    q.b1 = Wd1_bf + HD; q.ldb1 = HD+SD;
    q.kc0=32; q.kc1=34; q.kc2=34; q.kcPerZ=34;
    q.cb = hid_bf; q.ldcb = HD;
    q.bias0 = b_dec1; q.relu = 1;
    gemm_bf16<128,128><<<dim3(HD/128, BT/128, 1), 256, 0, stream>>>(q);
  }
  {
    GemmP q{};
    q.a0 = hid_bf; q.lda0 = HD;
    q.b0 = Wd2_bf; q.ldb0 = HD;
    q.kc0=q.kc1=q.kc2=32; q.kcPerZ=32;
    q.cf = (float*)d_out; q.ldc = OBSD;
    q.bias0 = b_dec2;
    gemm_bf16<128,128><<<dim3(OBSD/128, BT/128, 1), 256, 0, stream>>>(q);
  }
  rewdone_kernel<<<dim3(BT/4), 256, 0, stream>>>(det_bf, sto_bf, W_rew, b_rew, W_done, b_done,
      (float*)d_out + (long)BT*OBSD, (float*)d_out + (long)BT*OBSD + BT);
  kl_reduce<<<dim3(1), 256, 0, stream>>>(klrows, (float*)d_out + (long)BT*OBSD + 2*BT);
}

// Round 15
// 1585.409 us; speedup vs baseline: 2.2383x; 1.0470x over previous
//
#include <hip/hip_runtime.h>
#include <stdint.h>

#define BB 512
#define TT 64
#define OBSD 1024
#define ACTD 32
#define HD 1024
#define SD 64
#define BT (BB*TT)
#define G3 (3*HD)
#define STRD ((long)TT*HD)

typedef unsigned int uint32;
typedef unsigned long long ull;
typedef unsigned short u16;
typedef __attribute__((ext_vector_type(8))) short bf16x8;
typedef __attribute__((ext_vector_type(4))) float f32x4;

__device__ __forceinline__ float bf2f(u16 v){ uint32_t u = ((uint32_t)v)<<16; return __builtin_bit_cast(float,u); }
__device__ __forceinline__ u16 f2bf(float f){ uint32_t u = __builtin_bit_cast(uint32_t,f); uint32_t r = (u + 0x7FFFu + ((u>>16)&1u))>>16; return (u16)r; }
__device__ __forceinline__ float sigm(float x){ return 1.f/(1.f+expf(-x)); }
#define MFMA __builtin_amdgcn_mfma_f32_16x16x32_bf16

// width-16 async global->LDS (per-lane global src, wave-uniform LDS base + lane*16)
__device__ __forceinline__ void gload16(const u16* g, u16* l){
  __builtin_amdgcn_global_load_lds(
      (const __attribute__((address_space(1))) u16*)g,
      (__attribute__((address_space(3))) u16*)l, 16, 0, 0);
}

// ---------- f32 -> bf16 convert (RNE) ----------
__global__ void cvt_kernel(const float* __restrict__ in, u16* __restrict__ out, long n){
  long i = (long)blockIdx.x*blockDim.x + threadIdx.x;
  long st = (long)gridDim.x*blockDim.x;
  for (; i<n; i+=st) out[i] = f2bf(in[i]);
}

// ---------- generic bf16 MFMA GEMM (r11, gload_lds dbuf, tested) ----------
struct GemmP {
  const u16* a0; const u16* a1; const u16* a2;
  const u16* b0; const u16* b1; const u16* b2;
  long lda0, lda1, lda2, ldb0, ldb1, ldb2;
  int kc0, kc1, kc2, kcPerZ;
  float* cf; u16* cb;
  long ldc, ldcb, zstride;
  const float* bias0; const float* bias1;
  int relu;
};

template<int BM,int BN>
__global__ __launch_bounds__(256) void gemm_bf16(GemmP p){
  __shared__ __align__(16) u16 sAB[2][(BM+BN)*32];
  const int m0 = blockIdx.y*BM, n0 = blockIdx.x*BN;
  const int tid = threadIdx.x, lane = tid&63, wave = tid>>6;
  const int wm = (wave>>1)*(BM/2), wn = (wave&1)*(BN/2);
  constexpr int FM = BM/32, FN = BN/32;
  f32x4 acc[FM][FN] = {};
  const int cbeg = blockIdx.z*p.kcPerZ;
  int cend = cbeg + p.kcPerZ; if (cend > p.kc2) cend = p.kc2;
  const int kg = lane>>4, lr = lane&15;
  const int srow = lane>>2, scol = (lane&3)*8;

  auto STAGE = [&](int buf, int c){
    const u16* ap; const u16* bp; long lda, ldb; int kofs;
    if (c < p.kc0){ ap=p.a0; bp=p.b0; lda=p.lda0; ldb=p.ldb0; kofs=c*32; }
    else if (c < p.kc1){ ap=p.a1; bp=p.b1; lda=p.lda1; ldb=p.ldb1; kofs=(c-p.kc0)*32; }
    else { ap=p.a2; bp=p.b2; lda=p.lda2; ldb=p.ldb2; kofs=(c-p.kc1)*32; }
    u16* base = sAB[buf];
    #pragma unroll
    for (int it=0; it<BM/64; ++it){
      int row = it*64 + wave*16 + srow;
      gload16(ap + (long)(m0+row)*lda + kofs + scol,
              base + (it*64 + wave*16)*32);
    }
    #pragma unroll
    for (int it=0; it<BN/64; ++it){
      int row = it*64 + wave*16 + srow;
      gload16(bp + (long)(n0+row)*ldb + kofs + scol,
              base + BM*32 + (it*64 + wave*16)*32);
    }
  };

  STAGE(0, cbeg);
  for (int c=cbeg;c<cend;++c){
    const int cur = (c-cbeg)&1;
    asm volatile("s_waitcnt vmcnt(0)" ::: "memory");
    __syncthreads();
    if (c+1 < cend) STAGE(cur^1, c+1);
    const u16* sA = sAB[cur];
    const u16* sB = sAB[cur] + BM*32;
    bf16x8 af[FM], bfv[FN];
    #pragma unroll
    for (int i=0;i<FM;++i) af[i] = *(const bf16x8*)&sA[(wm+i*16+lr)*32 + kg*8];
    #pragma unroll
    for (int j=0;j<FN;++j) bfv[j] = *(const bf16x8*)&sB[(wn+j*16+lr)*32 + kg*8];
    #pragma unroll
    for (int i=0;i<FM;++i)
      #pragma unroll
      for (int j=0;j<FN;++j)
        acc[i][j] = MFMA(af[i], bfv[j], acc[i][j], 0,0,0);
    __syncthreads();
  }
  const bool partial = (gridDim.z > 1);
  float* cf = p.cf ? (p.cf + (partial ? (long)blockIdx.z*p.zstride : 0)) : nullptr;
  #pragma unroll
  for (int i=0;i<FM;++i){
    #pragma unroll
    for (int j=0;j<FN;++j){
      const int gr0 = m0 + wm + i*16 + kg*4;
      const int gc = n0 + wn + j*16 + lr;
      float bias = 0.f;
      if (!partial){
        if (p.bias0) bias += p.bias0[gc];
        if (p.bias1) bias += p.bias1[gc];
      }
      #pragma unroll
      for (int r=0;r<4;++r){
        float v = acc[i][j][r] + bias;
        if (p.relu) v = fmaxf(v, 0.f);
        const long row = gr0 + r;
        if (cf) cf[row*p.ldc + gc] = v;
        if (p.cb) p.cb[row*p.ldcb + gc] = f2bf(v);
      }
    }
  }
}

// ================= persistent cooperative scan (256 blocks, 1/CU) =================
struct ScanArgs {
  const u16* act; const u16* Wih; const u16* Whh;
  const float* b_ih; const float* b_hh;
  const u16* Wpos; const float* qemb; const float* eps;
  u16* det; u16* sto; float* qm; float* qs;
  uint32* slots; const u16* zeroB;
};

// Group-local (32-block) arrive-by-store barrier (r9-proven primitive).
__device__ __forceinline__ void gsync_g(uint32* slots, int m, int n, uint32 val){
  asm volatile("s_waitcnt vmcnt(0)" ::: "memory");
  __syncthreads();
  if (threadIdx.x == 0)
    __hip_atomic_store(&slots[m*64 + n], val, __ATOMIC_RELAXED, __HIP_MEMORY_SCOPE_AGENT);
  if (threadIdx.x < 32){
    while (__hip_atomic_load(&slots[m*64 + threadIdx.x], __ATOMIC_RELAXED,
                             __HIP_MEMORY_SCOPE_AGENT) < val)
      __builtin_amdgcn_s_sleep(2);
  }
  __syncthreads();
}

// LDS tile: unpadded [row][128 halves] (256 B rows), 16B-slot XOR swizzle.
// logical (row, c16) stored at slot c16 ^ (row & 15).
// Writes: thread slot = (tid&15) ^ srow (constant: (srow+16j)&15 == srow).
// Reads: row&15 == lr in all streams -> slot = (k*4+kg) ^ lr.
// Both sides 8-lanes-per-quad even spread => zero extra LDS cycles.

__global__ __launch_bounds__(256, 1) void scan_kernel(ScanArgs A){
  __shared__ __align__(16) u16 lds[(64+96)*128];
  u16* sA = lds; u16* sB = lds + 64*128;
  float* pf = (float*)lds;
  const int bid = blockIdx.x;
  const int tid = threadIdx.x, lane = tid&63, wave = tid>>6;
  const int lr = lane&15, kg = lane>>4;
  const int n = bid&31, m = bid>>5;       // n%8 -> XCD: W-slices L2-resident
  const int m0 = m*64, h0 = n*32;
  const int wrow = (wave&1)*32, wcol = (wave>>1)*16;

  const int srow = tid>>4;          // 0..15
  const int scu  = (tid&15)*8;      // 0..120 (global-side column, halves)
  const int scuS = ((tid&15) ^ srow)*8;   // swizzled LDS slot (halves)

  long whhb[6], wihb[6];
  #pragma unroll
  for (int i=0;i<6;++i){
    int br = srow + i*16;           // 0..95
    int gate = br>>5, hr = br&31;
    whhb[i] = (long)(gate*HD + h0 + hr)*HD + scu;
    wihb[i] = (long)(gate*HD + h0 + hr)*96 + scu;
  }

  // swapped-operand C layout: lane owns batch row (lr) x 4 consecutive h (kg*4+reg)
  const int h4 = h0 + wcol + kg*4;
  float bir[4], bhr[4], biz[4], bhz[4], bin[4], bhn[4];
  #pragma unroll
  for (int r=0;r<4;++r){
    bir[r]=A.b_ih[h4+r];      bhr[r]=A.b_hh[h4+r];
    biz[r]=A.b_ih[HD+h4+r];   bhz[r]=A.b_hh[HD+h4+r];
    bin[r]=A.b_ih[2*HD+h4+r]; bhn[r]=A.b_hh[2*HD+h4+r];
  }

  // distributed posterior tile: s-tile pj (16 s), row-tile prt (8 rows)
  const int pj = n & 3, prt = n >> 2;

  float dreg[2][4] = {{0.f,0.f,0.f,0.f},{0.f,0.f,0.f,0.f}};
  const bf16x8 zerov = {};

  // depth-3 register queue for A-fragments (det/sto/act); B single-depth (L2-hot)
  bf16x8 paQ[3][4], pb[6];
  auto loadA = [&](int tt, int g, bf16x8 (&dst)[4]){
    if (g < 8){
      if (tt > 0){
        const u16* s = A.det + (long)(tt-1)*HD + g*128 + scu;
        #pragma unroll
        for (int j=0;j<4;++j) dst[j] = *(const bf16x8*)(s + (long)(m0+srow+16*j)*STRD);
      } else { dst[0]=zerov; dst[1]=zerov; dst[2]=zerov; dst[3]=zerov; }
    } else {
      if (scu < 64){
        if (tt > 0){
          #pragma unroll
          for (int j=0;j<4;++j)
            dst[j] = *(const bf16x8*)(A.sto + (long)(m0+srow+16*j)*((long)TT*SD) + (long)(tt-1)*SD + scu);
        } else { dst[0]=zerov; dst[1]=zerov; dst[2]=zerov; dst[3]=zerov; }
      } else if (scu < 96){
        #pragma unroll
        for (int j=0;j<4;++j)
          dst[j] = *(const bf16x8*)(A.act + (long)(m0+srow+16*j)*((long)TT*ACTD) + (long)tt*ACTD + (scu-64));
      } else { dst[0]=zerov; dst[1]=zerov; dst[2]=zerov; dst[3]=zerov; }
    }
  };
  auto loadB = [&](int g){
    if (g < 8){
      #pragma unroll
      for (int i=0;i<6;++i) pb[i] = *(const bf16x8*)(A.Whh + whhb[i] + g*128);
    } else {
      #pragma unroll
      for (int i=0;i<6;++i) pb[i] = (scu < 96) ? *(const bf16x8*)(A.Wih + wihb[i]) : zerov;
    }
  };

  loadA(0, 0, paQ[0]); loadA(0, 1, paQ[1]); loadA(0, 2, paQ[2]); loadB(0);

  for (int t=0; t<TT; ++t){
    // ---------------- gates GEMM (9 K-groups of 128), depth-3 A pipeline ----------------
    f32x4 aR[2]={}, aZ[2]={}, aNd[2]={}, aNx[2]={};
    #pragma unroll
    for (int g=0; g<9; ++g){
      __syncthreads();
      #pragma unroll
      for (int j=0;j<4;++j) *(bf16x8*)&sA[(srow+16*j)*128 + scuS] = paQ[g%3][j];
      #pragma unroll
      for (int i=0;i<6;++i) *(bf16x8*)&sB[(srow+16*i)*128 + scuS] = pb[i];
      if (g < 8) loadB(g+1);
      if (g+3 <= 8) loadA(t, g+3, paQ[(g+3)%3]);
      __syncthreads();
      #pragma unroll
      for (int k=0;k<4;++k){
        const int sl = ((k*4+kg) ^ lr)*8;     // swizzled read slot (halves)
        bf16x8 a0v = *(const bf16x8*)&sA[(wrow+lr)*128 + sl];
        bf16x8 a1v = *(const bf16x8*)&sA[(wrow+16+lr)*128 + sl];
        bf16x8 b0 = *(const bf16x8*)&sB[(wcol+lr)*128 + sl];
        bf16x8 b1 = *(const bf16x8*)&sB[(32+wcol+lr)*128 + sl];
        bf16x8 b2 = *(const bf16x8*)&sB[(64+wcol+lr)*128 + sl];
        // swapped operands: C row-axis (kg*4+reg) = h, col-axis (lane&15) = batch
        aR[0] = MFMA(b0,a0v,aR[0],0,0,0); aR[1] = MFMA(b0,a1v,aR[1],0,0,0);
        aZ[0] = MFMA(b1,a0v,aZ[0],0,0,0); aZ[1] = MFMA(b1,a1v,aZ[1],0,0,0);
        if (g<8){ aNd[0] = MFMA(b2,a0v,aNd[0],0,0,0); aNd[1] = MFMA(b2,a1v,aNd[1],0,0,0); }
        else    { aNx[0] = MFMA(b2,a0v,aNx[0],0,0,0); aNx[1] = MFMA(b2,a1v,aNx[1],0,0,0); }
      }
    }
    // GRU epilogue; det written write-through (8B granules)
    #pragma unroll
    for (int rf=0;rf<2;++rf){
      const long brow = m0 + wrow + rf*16 + lr;
      u16 pk[4];
      #pragma unroll
      for (int r=0;r<4;++r){
        float rr = sigm(aR[rf][r]+bir[r]+bhr[r]);
        float z  = sigm(aZ[rf][r]+biz[r]+bhz[r]);
        float nn = tanhf(aNx[rf][r]+bin[r] + rr*(aNd[rf][r]+bhn[r]));
        float d = (1.f - z)*nn + z*dreg[rf][r];
        dreg[rf][r] = d;
        pk[r] = f2bf(d);
      }
      ull pv; __builtin_memcpy(&pv, pk, 8);
      __hip_atomic_store((ull*)(A.det + brow*STRD + (long)t*HD + h4), pv,
                         __ATOMIC_RELAXED, __HIP_MEMORY_SCOPE_AGENT);
    }
    gsync_g(A.slots, m, n, (uint32)(2*t+1));

    // ---------------- distributed posterior: 8 rows x (16 mean + 16 std) ----------------
    {
      f32x4 accM = {}, accS = {};
      const int k0 = wave*256;
      const u16* arow = A.det + (long)(m0 + prt*8 + (lr&7))*STRD + (long)t*HD + k0 + kg*8;
      const u16* bm = A.Wpos + (long)(pj*16 + lr)*(2*HD) + k0 + kg*8;
      const u16* bs = A.Wpos + (long)(64 + pj*16 + lr)*(2*HD) + k0 + kg*8;
      #pragma unroll
      for (int kk=0; kk<8; ++kk){
        bf16x8 af = *(const bf16x8*)(arow + kk*32);
        accM = MFMA(af, *(const bf16x8*)(bm + kk*32), accM, 0,0,0);
        accS = MFMA(af, *(const bf16x8*)(bs + kk*32), accS, 0,0,0);
      }
      #pragma unroll
      for (int r=0;r<4;++r){
        int rowt = kg*4 + r;
        pf[wave*512 + rowt*16 + lr]       = accM[r];
        pf[wave*512 + 256 + rowt*16 + lr] = accS[r];
      }
      __syncthreads();
      if (tid < 64){
        const int row = tid>>3;        // 0..7 (C rows 8..15 are duplicates)
        const int s2 = (tid&7)*2;
        const long grow = m0 + prt*8 + row;
        const float* qe = A.qemb + grow*((long)TT*128) + (long)t*128;
        const float* ep = A.eps  + grow*((long)TT*SD) + (long)t*SD;
        u16 spk[2];
        #pragma unroll
        for (int i=0;i<2;++i){
          int sl = s2 + i, sg = pj*16 + sl;
          float mean = pf[row*16+sl] + pf[512+row*16+sl] + pf[1024+row*16+sl] + pf[1536+row*16+sl];
          float rsv  = pf[256+row*16+sl] + pf[768+row*16+sl] + pf[1280+row*16+sl] + pf[1792+row*16+sl];
          mean += qe[sg];
          rsv  += qe[64+sg];
          float sp = fmaxf(rsv,0.f) + log1pf(expf(-fabsf(rsv)));
          float qs_ = sp + 1e-4f;
          float st = mean + ep[sg]*qs_;
          A.qm[grow*((long)TT*SD) + (long)t*SD + sg] = mean;
          A.qs[grow*((long)TT*SD) + (long)t*SD + sg] = qs_;
          spk[i] = f2bf(st);
        }
        uint32 pv; __builtin_memcpy(&pv, spk, 4);
        __hip_atomic_store((uint32*)(A.sto + grow*((long)TT*SD) + (long)t*SD + pj*16 + s2), pv,
                           __ATOMIC_RELAXED, __HIP_MEMORY_SCOPE_AGENT);
      }
      __syncthreads();
    }
    // prefetch next step's gates groups 0..2 (det(t) ready after barrier 1);
    // their MALL latency overlaps the barrier-2 wait.
    if (t+1 < TT){
      loadA(t+1, 0, paQ[0]);
      loadA(t+1, 1, paQ[1]);
      loadA(t+1, 2, paQ[2]);
      loadB(0);
    }
    gsync_g(A.slots, m, n, (uint32)(2*t+2));
  }
}

// ================= fallback per-step kernels (round-2, tested) =================
__global__ __launch_bounds__(256) void gru_step(
    const u16* __restrict__ sto_prev, long ssto,
    const u16* __restrict__ act_t,
    const u16* __restrict__ det_prev, long sdet,
    const u16* __restrict__ Wih, const u16* __restrict__ Whh,
    const float* __restrict__ b_ih, const float* __restrict__ b_hh,
    float* __restrict__ deterF, u16* __restrict__ det_bf_t){
  constexpr int SA = 40;
  __shared__ u16 sA[32*SA];
  __shared__ u16 sB[96*SA];
  const int id = blockIdx.x;
  const int n = (id&7) + ((id>>7)<<3);
  const int m = (id>>3)&15;
  const int m0 = m*32, h0 = n*32;
  const int tid = threadIdx.x, lane = tid&63, wave = tid>>6;
  const int wm = wave>>1, wn = wave&1;
  const int lr = lane&15, kg = lane>>4;

  f32x4 aR = {}, aZ = {}, aNd = {}, aNx = {};

  auto aAddr = [&](int c, int row, int sc)->const u16*{
    if (c < 32) return det_prev + (long)(m0+row)*sdet + c*32 + sc;
    if (c < 34) return sto_prev + (long)(m0+row)*ssto + (c-32)*32 + sc;
    return act_t + (long)(m0+row)*((long)TT*ACTD) + sc;
  };
  auto bAddr = [&](int c, int l)->const u16*{
    int row = l>>2, sc = (l&3)*8;
    int g = row>>5, hr = row&31;
    if (c < 32) return Whh + (long)(g*1024 + h0 + hr)*HD + c*32 + sc;
    return Wih + (long)(g*1024 + h0 + hr)*(SD+ACTD) + (c-32)*32 + sc;
  };

  bf16x8 rA, rB0, rB1;
  auto loadc = [&](int c){
    rB0 = *(const bf16x8*)bAddr(c, tid);
    if (tid < 128){
      rA  = *(const bf16x8*)aAddr(c, tid>>2, (tid&3)*8);
      rB1 = *(const bf16x8*)bAddr(c, 256+tid);
    }
  };

  loadc(0);
  for (int c=0; c<35; ++c){
    *(bf16x8*)&sB[(tid>>2)*SA + (tid&3)*8] = rB0;
    if (tid < 128){
      *(bf16x8*)&sA[(tid>>2)*SA + (tid&3)*8] = rA;
      int l = 256+tid;
      *(bf16x8*)&sB[(l>>2)*SA + (l&3)*8] = rB1;
    }
    if (c < 34) loadc(c+1);
    __syncthreads();
    bf16x8 af = *(const bf16x8*)&sA[(wm*16+lr)*SA + kg*8];
    bf16x8 b0 = *(const bf16x8*)&sB[(     wn*16+lr)*SA + kg*8];
    bf16x8 b1 = *(const bf16x8*)&sB[(32 + wn*16+lr)*SA + kg*8];
    bf16x8 b2 = *(const bf16x8*)&sB[(64 + wn*16+lr)*SA + kg*8];
    aR = MFMA(af,b0,aR,0,0,0);
    aZ = MFMA(af,b1,aZ,0,0,0);
    if (c < 32) aNd = MFMA(af,b2,aNd,0,0,0);
    else        aNx = MFMA(af,b2,aNx,0,0,0);
    __syncthreads();
  }

  const int col = h0 + wn*16 + lr;
  const float bir = b_ih[col],      bhr = b_hh[col];
  const float biz = b_ih[col+HD],   bhz = b_hh[col+HD];
  const float bin = b_ih[col+2*HD], bhn = b_hh[col+2*HD];
  #pragma unroll
  for (int reg=0; reg<4; ++reg){
    const int row = m0 + wm*16 + kg*4 + reg;
    float r = sigm(aR[reg] + bir + bhr);
    float z = sigm(aZ[reg] + biz + bhz);
    float nn = tanhf(aNx[reg] + bin + r*(aNd[reg] + bhn));
    const long fidx = (long)row*HD + col;
    float d = (1.f - z)*nn + z*deterF[fidx];
    deterF[fidx] = d;
    det_bf_t[(long)row*STRD + col] = f2bf(d);
  }
}

__global__ __launch_bounds__(256) void post_step(
    const u16* __restrict__ det_t,
    const u16* __restrict__ Wpos,
    const float* __restrict__ qemb_t,
    const float* __restrict__ eps_t,
    float* __restrict__ qm_t, float* __restrict__ qs_t, u16* __restrict__ sto_out){
  constexpr int SA = 40;
  __shared__ u16 sA4[4*16*SA];
  __shared__ u16 sB4[4*128*SA];
  const int m0 = blockIdx.x*16;
  const int tid = threadIdx.x, lane = tid&63, w = tid>>6;
  const int lr = lane&15, kg = lane>>4;

  f32x4 acc[8] = {};
  bf16x8 rA, rB[8];
  auto loadIter = [&](int i){
    #pragma unroll
    for (int rnd=0; rnd<8; ++rnd){
      int l = rnd*256 + tid;
      int q = l>>9, row = (l>>2)&127, sc = (l&3)*8;
      rB[rnd] = *(const bf16x8*)(Wpos + (long)row*(2*HD) + (q*8+i)*32 + sc);
    }
    { int q = tid>>6, row = (tid>>2)&15, sc = (tid&3)*8;
      rA = *(const bf16x8*)(det_t + (long)(m0+row)*STRD + (q*8+i)*32 + sc); }
  };

  loadIter(0);
  for (int i=0; i<8; ++i){
    #pragma unroll
    for (int rnd=0; rnd<8; ++rnd){
      int l = rnd*256 + tid;
      int q = l>>9, row = (l>>2)&127, sc = (l&3)*8;
      *(bf16x8*)&sB4[q*128*SA + row*SA + sc] = rB[rnd];
    }
    { int q = tid>>6, row = (tid>>2)&15, sc = (tid&3)*8;
      *(bf16x8*)&sA4[q*16*SA + row*SA + sc] = rA; }
    if (i < 7) loadIter(i+1);
    __syncthreads();
    bf16x8 af = *(const bf16x8*)&sA4[w*16*SA + lr*SA + kg*8];
    #pragma unroll
    for (int j=0; j<8; ++j){
      bf16x8 bf = *(const bf16x8*)&sB4[w*128*SA + (j*16+lr)*SA + kg*8];
      acc[j] = MFMA(af, bf, acc[j], 0,0,0);
    }
    __syncthreads();
  }

  float* pf = (float*)sB4;
  #pragma unroll
  for (int j=0; j<8; ++j)
    #pragma unroll
    for (int reg=0; reg<4; ++reg)
      pf[w*2048 + (kg*4+reg)*128 + j*16+lr] = acc[j][reg];
  __syncthreads();

  #pragma unroll
  for (int i=0; i<4; ++i){
    int p = tid + i*256;
    int row = p>>6, s = p&63;
    int b = m0 + row;
    float mval = pf[row*128+s]      + pf[2048+row*128+s]      + pf[4096+row*128+s]      + pf[6144+row*128+s];
    float rsv  = pf[row*128+64+s]   + pf[2048+row*128+64+s]   + pf[4096+row*128+64+s]   + pf[6144+row*128+64+s];
    mval += qemb_t[(long)b*((long)TT*128) + s];
    rsv  += qemb_t[(long)b*((long)TT*128) + 64 + s];
    float sp = fmaxf(rsv,0.f) + log1pf(expf(-fabsf(rsv)));
    float qsv = sp + 1e-4f;
    float e = eps_t[(long)b*((long)TT*SD) + s];
    float st = mval + e*qsv;
    qm_t[(long)b*((long)TT*SD) + s] = mval;
    qs_t[(long)b*((long)TT*SD) + s] = qsv;
    sto_out[(long)b*((long)TT*SD) + s] = f2bf(st);
  }
}

// ---------- KL / heads ----------
__global__ void kl_kernel(const float* __restrict__ pbuf, const float* __restrict__ qm,
                          const float* __restrict__ qs, float* __restrict__ klrows){
  int m = blockIdx.x*4 + (threadIdx.x>>6);
  int s = threadIdx.x & 63;
  float pm   = pbuf[(long)m*128 + s];
  float praw = pbuf[(long)m*128 + 64 + s];
  float ps = fmaxf(praw,0.f) + log1pf(expf(-fabsf(praw))) + 1e-4f;
  float qmv = qm[(long)m*64+s], qsv = qs[(long)m*64+s];
  float d = qmv - pm;
  float kl = logf(ps/qsv) + (qsv*qsv + d*d)/(2.f*ps*ps) - 0.5f;
  #pragma unroll
  for (int off=32; off; off>>=1) kl += __shfl_xor(kl, off);
  if (s==0) klrows[m] = kl*(1.f/64.f);
}

__global__ void kl_reduce(const float* __restrict__ klrows, float* __restrict__ out){
  __shared__ float sm[256];
  float a = 0.f;
  for (int i=threadIdx.x; i<BT; i+=256) a += klrows[i];
  sm[threadIdx.x]=a; __syncthreads();
  for (int off=128; off; off>>=1){ if ((int)threadIdx.x<off) sm[threadIdx.x]+=sm[threadIdx.x+off]; __syncthreads(); }
  if (threadIdx.x==0) out[0] = sm[0] / (float)BT;
}

__global__ void rewdone_kernel(const u16* __restrict__ det, const u16* __restrict__ sto,
    const float* __restrict__ Wr, const float* __restrict__ br,
    const float* __restrict__ Wd, const float* __restrict__ bd,
    float* __restrict__ orew, float* __restrict__ odone){
  int m = blockIdx.x*4 + (threadIdx.x>>6);
  int lane = threadIdx.x & 63;
  float ar=0.f, ad=0.f;
  for (int k=lane; k<HD+SD; k+=64){
    float f = (k<HD) ? bf2f(det[(long)m*HD+k]) : bf2f(sto[(long)m*SD + (k-HD)]);
    ar = fmaf(f, Wr[k], ar); ad = fmaf(f, Wd[k], ad);
  }
  #pragma unroll
  for (int off=32; off; off>>=1){ ar += __shfl_xor(ar, off); ad += __shfl_xor(ad, off); }
  if (lane==0){ orew[m]=ar+br[0]; odone[m]=ad+bd[0]; }
}

static char* carve(char*& base, size_t bytes){
  char* p = base; base += (bytes + 255) & ~(size_t)255; return p;
}

extern "C" void kernel_launch(void* const* d_in, const int* in_sizes, int n_in,
                              void* d_out, int out_size, void* d_ws, size_t ws_size,
                              hipStream_t stream) {
  const float* obs    = (const float*)d_in[0];
  const float* action = (const float*)d_in[1];
  const float* eps    = (const float*)d_in[2];
  const float* W_enc  = (const float*)d_in[3];
  const float* b_enc  = (const float*)d_in[4];
  const float* W_ih   = (const float*)d_in[5];
  const float* W_hh   = (const float*)d_in[6];
  const float* b_ih   = (const float*)d_in[7];
  const float* b_hh   = (const float*)d_in[8];
  const float* W_prior= (const float*)d_in[9];
  const float* b_prior= (const float*)d_in[10];
  const float* W_post = (const float*)d_in[11];
  const float* b_post = (const float*)d_in[12];
  const float* W_dec1 = (const float*)d_in[13];
  const float* b_dec1 = (const float*)d_in[14];
  const float* W_dec2 = (const float*)d_in[15];
  const float* b_dec2 = (const float*)d_in[16];
  const float* W_rew  = (const float*)d_in[17];
  const float* b_rew  = (const float*)d_in[18];
  const float* W_done = (const float*)d_in[19];
  const float* b_done = (const float*)d_in[20];

  char* w = (char*)d_ws;
  u16* obs_bf  = (u16*)carve(w, (size_t)BT*OBSD*2);   // later reused as hid_bf
  u16* emb_bf  = (u16*)carve(w, (size_t)BT*HD*2);
  u16* det_bf  = (u16*)carve(w, (size_t)BT*HD*2);
  u16* sto_bf  = (u16*)carve(w, (size_t)BT*SD*2);
  u16* act_bf  = (u16*)carve(w, (size_t)BT*ACTD*2);
  u16* Wenc_bf = (u16*)carve(w, (size_t)HD*OBSD*2);
  u16* Wih_bf  = (u16*)carve(w, (size_t)G3*(SD+ACTD)*2);
  u16* Whh_bf  = (u16*)carve(w, (size_t)G3*HD*2);
  u16* Wpri_bf = (u16*)carve(w, (size_t)2*SD*HD*2);
  u16* Wpos_bf = (u16*)carve(w, (size_t)2*SD*2*HD*2);
  u16* Wd1_bf  = (u16*)carve(w, (size_t)HD*(HD+SD)*2);
  u16* Wd2_bf  = (u16*)carve(w, (size_t)OBSD*HD*2);
  u16* zero_bf = (u16*)carve(w, 4096);
  float* deterF = (float*)carve(w, (size_t)BB*HD*4);
  float* qemb   = (float*)carve(w, (size_t)BT*128*4);
  float* qm_all = (float*)carve(w, (size_t)BT*SD*4);
  float* qs_all = (float*)carve(w, (size_t)BT*SD*4);
  float* p_buf  = (float*)carve(w, (size_t)BT*2*SD*4);
  float* klrows = (float*)carve(w, (size_t)BT*4);
  uint32* syncb = (uint32*)carve(w, 8192);
  u16* hid_bf = obs_bf;

  if ((size_t)(w - (char*)d_ws) > ws_size){
    hipMemsetAsync(d_out, 0xFF, 4, stream);
    return;
  }

  auto cvt = [&](const float* in, u16* out, long n){
    cvt_kernel<<<dim3(2048), dim3(256), 0, stream>>>(in, out, n);
  };
  cvt(obs, obs_bf, (long)BT*OBSD);
  cvt(action, act_bf, (long)BT*ACTD);
  cvt(W_enc, Wenc_bf, (long)HD*OBSD);
  cvt(W_ih, Wih_bf, (long)G3*(SD+ACTD));
  cvt(W_hh, Whh_bf, (long)G3*HD);
  cvt(W_prior, Wpri_bf, (long)2*SD*HD);
  cvt(W_post, Wpos_bf, (long)2*SD*2*HD);
  cvt(W_dec1, Wd1_bf, (long)HD*(HD+SD));
  cvt(W_dec2, Wd2_bf, (long)OBSD*HD);
  hipMemsetAsync(zero_bf, 0, 4096, stream);
  hipMemsetAsync(deterF, 0, (size_t)BB*HD*4, stream);
  hipMemsetAsync(syncb, 0, 8192, stream);

  // ---- Phase 1a: encoder
  {
    GemmP q{};
    q.a0 = obs_bf;  q.lda0 = OBSD;
    q.b0 = Wenc_bf; q.ldb0 = OBSD;
    q.kc0=q.kc1=q.kc2=32; q.kcPerZ=32;
    q.cb = emb_bf; q.ldcb = HD;
    q.bias0 = b_enc; q.relu = 1;
    gemm_bf16<128,128><<<dim3(HD/128, BT/128, 1), 256, 0, stream>>>(q);
  }
  // ---- Phase 1b: Qemb
  {
    GemmP q{};
    q.a0 = emb_bf;       q.lda0 = HD;
    q.b0 = Wpos_bf + HD; q.ldb0 = 2*HD;
    q.kc0=q.kc1=q.kc2=32; q.kcPerZ=32;
    q.cf = qemb; q.ldc = 128;
    q.bias0 = b_post;
    gemm_bf16<64,64><<<dim3(128/64, BT/64, 1), 256, 0, stream>>>(q);
  }

  // ---- Phase 2: cooperative persistent scan (256 blocks), fallback to per-step
  {
    ScanArgs sa;
    sa.act = act_bf; sa.Wih = Wih_bf; sa.Whh = Whh_bf;
    sa.b_ih = b_ih; sa.b_hh = b_hh;
    sa.Wpos = Wpos_bf; sa.qemb = qemb; sa.eps = eps;
    sa.det = det_bf; sa.sto = sto_bf; sa.qm = qm_all; sa.qs = qs_all;
    sa.slots = syncb; sa.zeroB = zero_bf;
    void* kargs[] = { (void*)&sa };
    hipError_t cerr = hipLaunchCooperativeKernel((const void*)scan_kernel,
        dim3(256), dim3(256), kargs, 0, stream);
    if (cerr != hipSuccess){
      for (int t=0; t<TT; ++t){
        const u16* sto_p = (t==0) ? zero_bf : (sto_bf + (long)(t-1)*SD);
        long ssto        = (t==0) ? 0 : (long)TT*SD;
        const u16* det_p = (t==0) ? zero_bf : (det_bf + (long)(t-1)*HD);
        long sdet        = (t==0) ? 0 : STRD;
        gru_step<<<dim3(512), 256, 0, stream>>>(sto_p, ssto, act_bf + (long)t*ACTD,
            det_p, sdet, Wih_bf, Whh_bf, b_ih, b_hh, deterF, det_bf + (long)t*HD);
        post_step<<<dim3(32), 256, 0, stream>>>(det_bf + (long)t*HD, Wpos_bf,
            qemb + (long)t*128, eps + (long)t*SD,
            qm_all + (long)t*SD, qs_all + (long)t*SD, sto_bf + (long)t*SD);
      }
    }
  }

  // ---- Phase 3: batched heads ----
  {
    GemmP q{};
    q.a0 = det_bf;  q.lda0 = HD;
    q.b0 = Wpri_bf; q.ldb0 = HD;
    q.kc0=q.kc1=q.kc2=32; q.kcPerZ=32;
    q.cf = p_buf; q.ldc = 2*SD;
    q.bias0 = b_prior;
    gemm_bf16<64,64><<<dim3(2*SD/64, BT/64, 1), 256, 0, stream>>>(q);
  }
  kl_kernel<<<dim3(BT/4), 256, 0, stream>>>(p_buf, qm_all, qs_all, klrows);
  {
    GemmP q{};
    q.a0 = det_bf; q.lda0 = HD;
    q.a1 = sto_bf; q.lda1 = SD;
    q.b0 = Wd1_bf;      q.ldb0 = HD+SD;
    q.b1 = Wd1_bf + HD; q.ldb1 = HD+SD;
    q.kc0=32; q.kc1=34; q.kc2=34; q.kcPerZ=34;
    q.cb = hid_bf; q.ldcb = HD;
    q.bias0 = b_dec1; q.relu = 1;
    gemm_bf16<128,128><<<dim3(HD/128, BT/128, 1), 256, 0, stream>>>(q);
  }
  {
    GemmP q{};
    q.a0 = hid_bf; q.lda0 = HD;
    q.b0 = Wd2_bf; q.ldb0 = HD;
    q.kc0=q.kc1=q.kc2=32; q.kcPerZ=32;
    q.cf = (float*)d_out; q.ldc = OBSD;
    q.bias0 = b_dec2;
    gemm_bf16<128,128><<<dim3(OBSD/128, BT/128, 1), 256, 0, stream>>>(q);
  }
  rewdone_kernel<<<dim3(BT/4), 256, 0, stream>>>(det_bf, sto_bf, W_rew, b_rew, W_done, b_done,
      (float*)d_out + (long)BT*OBSD, (float*)d_out + (long)BT*OBSD + BT);
  kl_reduce<<<dim3(1), 256, 0, stream>>>(klrows, (float*)d_out + (long)BT*OBSD + 2*BT);
}